// Round 12
// baseline (206.657 us; speedup 1.0000x reference)
//
#include <hip/hip_runtime.h>
#include <hip/hip_bf16.h>

#define N_NODES 50000
#define F_IN 128
#define HID 128
#define N_OUT 16
#define HEADS 4
#define EL 800000
#define EG 200000
#define NEG_SLOPE 0.2f
#define NB 196    // buckets of 256 nodes
#define GB 391    // ceil(50000/128)

typedef short bf16x8 __attribute__((ext_vector_type(8)));
typedef float f32x4 __attribute__((ext_vector_type(4)));
typedef float f32x2 __attribute__((ext_vector_type(2)));

static __device__ __forceinline__ float lrelu(float x) {
    return x > 0.f ? x : NEG_SLOPE * x;
}
static __device__ __forceinline__ unsigned short f2b(float f) {
    __hip_bfloat16 h = __float2bfloat16(f);
    return *reinterpret_cast<unsigned short*>(&h);
}
static __device__ __forceinline__ unsigned char f2fp8(float f) {
    unsigned pk = __builtin_amdgcn_cvt_pk_fp8_f32(f, f, 0, false);
    return (unsigned char)(pk & 0xFF);
}
static __device__ __forceinline__ f32x2 fp8x2_to_f32(unsigned u) {
    return __builtin_amdgcn_cvt_pk_f32_fp8((int)u, false);
}
static __device__ __forceinline__ float rdlane_f(float v, int l) {
    return __int_as_float(__builtin_amdgcn_readlane(__float_as_int(v), l));
}

// ---------- D1: weight conversions + bucket histogram ----------
__global__ __launch_bounds__(256) void conv_hist(
    const float* __restrict__ W1, unsigned short* __restrict__ W1t,
    const float* __restrict__ Wg, unsigned short* __restrict__ Wgt,
    const float* __restrict__ Wa, unsigned short* __restrict__ Wat,
    const float* __restrict__ Wp, unsigned short* __restrict__ Wpt,
    const int* __restrict__ ldst, const int* __restrict__ gdst, int* __restrict__ ghist)
{
    int b = blockIdx.x, t = threadIdx.x;
    if (b < 64) {                         // W1 [128][128] -> [n][k]
        int idx = b * 256 + t;
        int k = idx >> 7, n = idx & 127;
        W1t[n * 128 + k] = f2b(W1[idx]);
    } else if (b < 128) {                 // Wg
        int idx = (b - 64) * 256 + t;
        int k = idx >> 7, n = idx & 127;
        Wgt[n * 128 + k] = f2b(Wg[idx]);
    } else if (b < 384) {                 // Wa [128][512] -> [512][128]
        int idx = (b - 128) * 256 + t;
        int k = idx >> 9, n = idx & 511;
        Wat[(size_t)n * 128 + k] = f2b(Wa[idx]);
    } else if (b < 512) {                 // Wp [256][128] -> [128][256]
        int idx = (b - 384) * 256 + t;
        int k = idx >> 7, n = idx & 127;
        Wpt[(size_t)n * 256 + k] = f2b(Wp[idx]);
    } else {                              // bucket histogram
        __shared__ int lh[NB];
        int blk = b - 512;
        bool loc = blk < 196;
        const int* dstp = loc ? ldst : gdst;
        int nE = loc ? EL : EG;
        int* gh = ghist + (loc ? 0 : NB);
        int start = (loc ? blk : blk - 196) * 4096;
        if (t < NB) lh[t] = 0;
        __syncthreads();
        #pragma unroll
        for (int i = 0; i < 16; i++) {
            int e = start + i * 256 + t;
            if (e < nE) atomicAdd(&lh[dstp[e] >> 8], 1);
        }
        __syncthreads();
        if (t < NB && lh[t]) atomicAdd(&gh[t], lh[t]);
    }
}

// ---------- D2: bucket scan (blocks 0-1) + gemm_x (blocks 2..392) ----------
__global__ __launch_bounds__(256) void scan_gemmx(
    const int* __restrict__ ghist, int* __restrict__ bbase, int* __restrict__ gcur,
    const float* __restrict__ A, const unsigned short* __restrict__ Bt,
    const float* __restrict__ bias, unsigned short* __restrict__ out, int M)
{
    __shared__ unsigned short As[128 * 128];
    __shared__ unsigned short Bs[128 * 128];
    int tid = threadIdx.x;
    if (blockIdx.x < 2) {
        int* s = (int*)As;
        int g = blockIdx.x, t = tid;
        int v = (t < NB) ? ghist[g * NB + t] : 0;
        s[t] = v;
        __syncthreads();
        for (int off = 1; off < 256; off <<= 1) {
            int u = (t >= off) ? s[t - off] : 0;
            __syncthreads();
            s[t] += u;
            __syncthreads();
        }
        if (t < NB) {
            bbase[g * (NB + 1) + t] = s[t] - v;
            gcur[g * NB + t] = s[t] - v;
        }
        if (t == NB - 1) bbase[g * (NB + 1) + NB] = s[t];
        return;
    }
    int lane = tid & 63, w = tid >> 6;
    int wr = w >> 1, wc = w & 1;
    int l16 = lane & 15, lhi = lane >> 4;
    int m0 = (blockIdx.x - 2) * 128;
    f32x4 acc[4][4] = {};
    #pragma unroll
    for (int i = 0; i < 8; i++) {
        int u = tid + i * 256;
        int row = u >> 4, e0 = (u & 15) << 3;
        int sw = e0 ^ ((row & 7) << 3);
        int gr = m0 + row;
        unsigned short pb[8] = {};
        if (gr < M) {
            float4 a0 = *(const float4*)(A + (size_t)gr * 128 + e0);
            float4 a1 = *(const float4*)(A + (size_t)gr * 128 + e0 + 4);
            pb[0] = f2b(a0.x); pb[1] = f2b(a0.y); pb[2] = f2b(a0.z); pb[3] = f2b(a0.w);
            pb[4] = f2b(a1.x); pb[5] = f2b(a1.y); pb[6] = f2b(a1.z); pb[7] = f2b(a1.w);
        }
        *(bf16x8*)(As + row * 128 + sw) = *(bf16x8*)pb;
        bf16x8 vb = *(const bf16x8*)(Bt + (size_t)row * 128 + e0);
        *(bf16x8*)(Bs + row * 128 + sw) = vb;
    }
    __syncthreads();
    #pragma unroll
    for (int kk = 0; kk < 4; kk++) {
        int ke = kk * 32 + lhi * 8;
        bf16x8 af[4], bfr[4];
        #pragma unroll
        for (int m = 0; m < 4; m++) {
            int r = wr * 64 + m * 16 + l16;
            af[m] = *(const bf16x8*)(As + r * 128 + (ke ^ ((r & 7) << 3)));
        }
        #pragma unroll
        for (int n = 0; n < 4; n++) {
            int r = wc * 64 + n * 16 + l16;
            bfr[n] = *(const bf16x8*)(Bs + r * 128 + (ke ^ ((r & 7) << 3)));
        }
        #pragma unroll
        for (int m = 0; m < 4; m++)
            #pragma unroll
            for (int n = 0; n < 4; n++)
                acc[m][n] = __builtin_amdgcn_mfma_f32_16x16x32_bf16(af[m], bfr[n], acc[m][n], 0, 0, 0);
    }
    #pragma unroll
    for (int m = 0; m < 4; m++) {
        #pragma unroll
        for (int r = 0; r < 4; r++) {
            int row_g = m0 + wr * 64 + m * 16 + lhi * 4 + r;
            if (row_g >= M) continue;
            #pragma unroll
            for (int n = 0; n < 4; n++) {
                int col_g = wc * 64 + n * 16 + l16;
                float v = fmaxf(acc[m][n][r] + bias[col_g], 0.f);
                out[(size_t)row_g * 128 + col_g] = f2b(v);
            }
        }
    }
}

// ---------- D3: gemm_gw5 (blocks 0..390, NO dinv scaling) || bucket_part (391..635) ----------
__global__ __launch_bounds__(256) void part_gw5(
    const unsigned short* __restrict__ A, const unsigned short* __restrict__ Wgt,
    const unsigned short* __restrict__ Wat,
    unsigned char* __restrict__ xw_g8, unsigned char* __restrict__ xw_a8, int M,
    const float* __restrict__ atts, const float* __restrict__ attd,
    float* __restrict__ a_s, float* __restrict__ a_d,
    const int* __restrict__ lsrc, const int* __restrict__ ldst,
    const int* __restrict__ gsrc, const int* __restrict__ gdst,
    int* __restrict__ gcur, unsigned* __restrict__ ebuf_l, unsigned* __restrict__ ebuf_g)
{
    __shared__ unsigned short As[128 * 128];
    __shared__ unsigned short Bs[128 * 128];
    __shared__ float sas[128], sad[128];
    int tid = threadIdx.x;
    if (blockIdx.x >= GB) {
        // ---- bucket_part ----
        int* lhist = (int*)As;
        int* lbase = ((int*)As) + 256;
        int blk = blockIdx.x - GB, t = tid;
        bool loc = blk < 196;
        const int* srcp = loc ? lsrc : gsrc;
        const int* dstp = loc ? ldst : gdst;
        int nE = loc ? EL : EG;
        unsigned* ebuf = loc ? ebuf_l : ebuf_g;
        int* cur = gcur + (loc ? 0 : NB);
        int start = (loc ? blk : blk - 196) * 4096;
        if (t < NB) lhist[t] = 0;
        __syncthreads();
        unsigned pk[16];
        #pragma unroll
        for (int i = 0; i < 16; i++) {
            int e = start + i * 256 + t;
            if (e < nE) {
                unsigned d = (unsigned)dstp[e];
                pk[i] = (d << 16) | (unsigned)srcp[e];
                atomicAdd(&lhist[d >> 8], 1);
            } else pk[i] = 0xFFFFFFFFu;
        }
        __syncthreads();
        if (t < NB) lbase[t] = atomicAdd(&cur[t], lhist[t]);
        __syncthreads();
        if (t < NB) lhist[t] = 0;
        __syncthreads();
        #pragma unroll
        for (int i = 0; i < 16; i++) {
            unsigned b = pk[i] >> 24;
            if (b < NB) {
                int r = atomicAdd(&lhist[b], 1);
                ebuf[lbase[b] + r] = pk[i];
            }
        }
        return;
    }
    // ---- gemm_gw5 ----
    int lane = tid & 63, w = tid >> 6;
    int wr = w >> 1, wc = w & 1;
    int l16 = lane & 15, lhi = lane >> 4;
    int m0 = blockIdx.x * 128;
    #pragma unroll
    for (int i = 0; i < 8; i++) {
        int u = tid + i * 256;
        int row = u >> 4, e0 = (u & 15) << 3;
        int sw = e0 ^ ((row & 7) << 3);
        bf16x8 va = {};
        int gr = m0 + row;
        if (gr < M) va = *(const bf16x8*)(A + (size_t)gr * 128 + e0);
        *(bf16x8*)(As + row * 128 + sw) = va;
    }
    for (int p = 0; p < 5; p++) {
        const unsigned short* Bt = (p == 0) ? Wgt : (Wat + (size_t)(p - 1) * 128 * 128);
        __syncthreads();
        #pragma unroll
        for (int i = 0; i < 8; i++) {
            int u = tid + i * 256;
            int row = u >> 4, e0 = (u & 15) << 3;
            int sw = e0 ^ ((row & 7) << 3);
            bf16x8 vb = *(const bf16x8*)(Bt + (size_t)row * 128 + e0);
            *(bf16x8*)(Bs + row * 128 + sw) = vb;
        }
        if (tid < 128) { sas[tid] = 0.f; sad[tid] = 0.f; }
        __syncthreads();
        f32x4 acc[4][4] = {};
        #pragma unroll
        for (int kk = 0; kk < 4; kk++) {
            int ke = kk * 32 + lhi * 8;
            bf16x8 af[4], bfr[4];
            #pragma unroll
            for (int m = 0; m < 4; m++) {
                int r = wr * 64 + m * 16 + l16;
                af[m] = *(const bf16x8*)(As + r * 128 + (ke ^ ((r & 7) << 3)));
            }
            #pragma unroll
            for (int n = 0; n < 4; n++) {
                int r = wc * 64 + n * 16 + l16;
                bfr[n] = *(const bf16x8*)(Bs + r * 128 + (ke ^ ((r & 7) << 3)));
            }
            #pragma unroll
            for (int m = 0; m < 4; m++)
                #pragma unroll
                for (int n = 0; n < 4; n++)
                    acc[m][n] = __builtin_amdgcn_mfma_f32_16x16x32_bf16(af[m], bfr[n], acc[m][n], 0, 0, 0);
        }
        if (p == 0) {
            #pragma unroll
            for (int m = 0; m < 4; m++)
                #pragma unroll
                for (int r = 0; r < 4; r++) {
                    int row_g = m0 + wr * 64 + m * 16 + lhi * 4 + r;
                    if (row_g >= M) continue;
                    #pragma unroll
                    for (int n = 0; n < 4; n++) {
                        int col_g = wc * 64 + n * 16 + l16;
                        xw_g8[(size_t)row_g * 128 + col_g] = f2fp8(acc[m][n][r]);
                    }
                }
        } else {
            int head = p - 1;
            float ats[4], atd[4];
            #pragma unroll
            for (int n = 0; n < 4; n++) {
                int cl = wc * 64 + n * 16 + l16;
                ats[n] = atts[head * 128 + cl];
                atd[n] = attd[head * 128 + cl];
            }
            #pragma unroll
            for (int m = 0; m < 4; m++) {
                #pragma unroll
                for (int r = 0; r < 4; r++) {
                    int row_l = wr * 64 + m * 16 + lhi * 4 + r;
                    int row_g = m0 + row_l;
                    float ps = 0.f, pd = 0.f;
                    #pragma unroll
                    for (int n = 0; n < 4; n++) {
                        float v = acc[m][n][r];
                        ps = fmaf(v, ats[n], ps);
                        pd = fmaf(v, atd[n], pd);
                        if (row_g < M) {
                            int col_g = head * 128 + wc * 64 + n * 16 + l16;
                            xw_a8[(size_t)row_g * 512 + col_g] = f2fp8(v);
                        }
                    }
                    #pragma unroll
                    for (int off = 1; off < 16; off <<= 1) {
                        ps += __shfl_xor(ps, off);
                        pd += __shfl_xor(pd, off);
                    }
                    if (l16 == 0) {
                        atomicAdd(&sas[row_l], ps);
                        atomicAdd(&sad[row_l], pd);
                    }
                }
            }
            __syncthreads();
            if (tid < 128) {
                int row_g = m0 + tid;
                if (row_g < M) {
                    a_s[(size_t)row_g * 4 + head] = sas[tid];
                    a_d[(size_t)row_g * 4 + head] = sad[tid];
                }
            }
        }
    }
}

// ---------- D4: per-bucket fine CSR + dinv + in-place dinv-rescale of xw_g8 ----------
__global__ __launch_bounds__(256) void bucket_csr(
    const unsigned* __restrict__ ebuf_l, const unsigned* __restrict__ ebuf_g,
    const int* __restrict__ bbase,
    int* __restrict__ offs_l, int* __restrict__ offs_g,
    unsigned short* __restrict__ csr_l, unsigned short* __restrict__ csr_g,
    float* __restrict__ dinv, unsigned* __restrict__ xwg32)
{
    __shared__ int cnt[256], s[256], cur[256];
    __shared__ float sdinv[256];
    int blk = blockIdx.x, t = threadIdx.x;
    bool loc = blk < 196;
    int b = loc ? blk : blk - 196;
    const unsigned* ebuf = loc ? ebuf_l : ebuf_g;
    const int* bb = bbase + (loc ? 0 : NB + 1);
    int* offs = loc ? offs_l : offs_g;
    unsigned short* csr = loc ? csr_l : csr_g;
    int rs = bb[b], re = bb[b + 1];
    cnt[t] = 0;
    __syncthreads();
    for (int i = rs + t; i < re; i += 256) atomicAdd(&cnt[(ebuf[i] >> 16) & 255], 1);
    __syncthreads();
    int v = cnt[t];
    s[t] = v;
    __syncthreads();
    for (int off = 1; off < 256; off <<= 1) {
        int u = (t >= off) ? s[t - off] : 0;
        __syncthreads();
        s[t] += u;
        __syncthreads();
    }
    int excl = s[t] - v;
    int node = b * 256 + t;
    cur[t] = rs + excl;
    float dv = rsqrtf((float)(v + 1));
    if (node < N_NODES) {
        offs[node] = rs + excl;
        if (loc) dinv[node] = dv;
    }
    sdinv[t] = dv;
    if (blk == 0 && t == 0) offs_l[N_NODES] = EL;
    if (blk == 196 && t == 0) offs_g[N_NODES] = EG;
    __syncthreads();
    for (int i = rs + t; i < re; i += 256) {
        unsigned pk = ebuf[i];
        int r = atomicAdd(&cur[(pk >> 16) & 255], 1);
        csr[r] = (unsigned short)(pk & 0xFFFFu);
    }
    if (loc) {
        // in-place rescale of this bucket's xw_g8 rows by dinv (coalesced u32 walk)
        size_t base_u = (size_t)b * 256 * 32;
        for (int u = t; u < 256 * 32; u += 256) {
            int nl = u >> 5;
            int nodeg = b * 256 + nl;
            if (nodeg >= N_NODES) break;
            unsigned wv = xwg32[base_u + u];
            f32x2 lo = __builtin_amdgcn_cvt_pk_f32_fp8((int)wv, false);
            f32x2 hi = __builtin_amdgcn_cvt_pk_f32_fp8((int)wv, true);
            float dvn = sdinv[nl];
            lo *= dvn; hi *= dvn;
            unsigned pk2 = __builtin_amdgcn_cvt_pk_fp8_f32(lo[0], lo[1], 0, false);
            pk2 = __builtin_amdgcn_cvt_pk_fp8_f32(hi[0], hi[1], pk2, true);
            xwg32[base_u + u] = pk2;
        }
    }
}

// ---------- D5: fused gathers (unchanged structure) ----------
__global__ __launch_bounds__(256) void fused_gather(
    const int* __restrict__ offs_l, const unsigned short* __restrict__ csr_l,
    const unsigned char* __restrict__ xw_g8, const float* __restrict__ dinv,
    const float* __restrict__ bg,
    const int* __restrict__ offs_g, const unsigned short* __restrict__ csr_g,
    const float* __restrict__ a_s, const float* __restrict__ a_d,
    const unsigned char* __restrict__ xw_a8, const float* __restrict__ ba,
    unsigned short* __restrict__ xcomb)
{
    int blk = blockIdx.x;
    int tid = threadIdx.x;
    int lane = tid & 63;
    int g = lane >> 4, q = lane & 15;
    if (blk < 12500) {
        int d = (blk * 256 + tid) >> 6;
        if (d >= N_NODES) return;
        int base = offs_l[d], end = offs_l[d + 1];
        unsigned goff = (unsigned)q * 8u;
        f32x2 a0 = {0.f, 0.f}, a1 = {0.f, 0.f}, a2 = {0.f, 0.f}, a3 = {0.f, 0.f};
        for (int i = base; i < end; ) {
            int chunk = min(64, end - i);
            int sv = (lane < chunk) ? (int)csr_l[i + lane] : 0;
            int nst = (chunk + 3) >> 2;
            int j = 0;
            for (; j + 2 <= nst; j += 2) {
                int eA = j * 4 + g, eB = eA + 4;
                int sA = __shfl(sv, eA);
                int sB = __shfl(sv, eB);
                float mkA = (eA < chunk) ? 1.f : 0.f;
                float mkB = (eB < chunk) ? 1.f : 0.f;
                uint2 vA = *(const uint2*)(xw_g8 + (((unsigned)sA) << 7) + goff);
                uint2 vB = *(const uint2*)(xw_g8 + (((unsigned)sB) << 7) + goff);
                f32x2 mA = {mkA, mkA}, mB = {mkB, mkB};
                a0 += __builtin_amdgcn_cvt_pk_f32_fp8((int)vA.x, false) * mA;
                a1 += __builtin_amdgcn_cvt_pk_f32_fp8((int)vA.x, true) * mA;
                a2 += __builtin_amdgcn_cvt_pk_f32_fp8((int)vA.y, false) * mA;
                a3 += __builtin_amdgcn_cvt_pk_f32_fp8((int)vA.y, true) * mA;
                a0 += __builtin_amdgcn_cvt_pk_f32_fp8((int)vB.x, false) * mB;
                a1 += __builtin_amdgcn_cvt_pk_f32_fp8((int)vB.x, true) * mB;
                a2 += __builtin_amdgcn_cvt_pk_f32_fp8((int)vB.y, false) * mB;
                a3 += __builtin_amdgcn_cvt_pk_f32_fp8((int)vB.y, true) * mB;
            }
            for (; j < nst; j++) {
                int e = j * 4 + g;
                int s = __shfl(sv, e);
                float mk = (e < chunk) ? 1.f : 0.f;
                f32x2 m2 = {mk, mk};
                uint2 v = *(const uint2*)(xw_g8 + (((unsigned)s) << 7) + goff);
                a0 += __builtin_amdgcn_cvt_pk_f32_fp8((int)v.x, false) * m2;
                a1 += __builtin_amdgcn_cvt_pk_f32_fp8((int)v.x, true) * m2;
                a2 += __builtin_amdgcn_cvt_pk_f32_fp8((int)v.y, false) * m2;
                a3 += __builtin_amdgcn_cvt_pk_f32_fp8((int)v.y, true) * m2;
            }
            i += chunk;
        }
        float av[8] = {a0[0], a0[1], a1[0], a1[1], a2[0], a2[1], a3[0], a3[1]};
        #pragma unroll
        for (int k = 0; k < 8; k++) {
            av[k] += __shfl_xor(av[k], 16);
            av[k] += __shfl_xor(av[k], 32);
        }
        if (g == 0) {
            float dd = dinv[d];
            uint2 sv2 = *(const uint2*)(xw_g8 + (((unsigned)d) << 7) + goff);
            f32x2 s0 = fp8x2_to_f32(sv2.x & 0xFFFFu);
            f32x2 s1 = __builtin_amdgcn_cvt_pk_f32_fp8((int)sv2.x, true);
            f32x2 s2 = fp8x2_to_f32(sv2.y & 0xFFFFu);
            f32x2 s3 = __builtin_amdgcn_cvt_pk_f32_fp8((int)sv2.y, true);
            float sf[8] = {s0[0], s0[1], s1[0], s1[1], s2[0], s2[1], s3[0], s3[1]};
            float4 b0 = *(const float4*)(bg + q * 8);
            float4 b1 = *(const float4*)(bg + q * 8 + 4);
            float bb[8] = {b0.x, b0.y, b0.z, b0.w, b1.x, b1.y, b1.z, b1.w};
            unsigned o[4];
            #pragma unroll
            for (int k = 0; k < 4; k++) {
                float v0 = fmaxf(dd * (av[2 * k] + sf[2 * k]) + bb[2 * k], 0.f);
                float v1 = fmaxf(dd * (av[2 * k + 1] + sf[2 * k + 1]) + bb[2 * k + 1], 0.f);
                o[k] = (unsigned)f2b(v0) | ((unsigned)f2b(v1) << 16);
            }
            *(uint4*)(xcomb + (size_t)d * 256 + q * 8) = make_uint4(o[0], o[1], o[2], o[3]);
        }
    } else {
        int d = ((blk - 12500) * 256 + tid) >> 6;
        if (d >= N_NODES) return;
        int base = offs_g[d], end = offs_g[d + 1];
        int deg = end - base;
        if (deg <= 16) {
            float ad_g = a_d[(size_t)d * 4 + g];
            float es = lrelu(a_s[(size_t)d * 4 + g] + ad_g);
            int sv = (q < deg) ? (int)csr_g[base + q] : 0;
            float asg = a_s[(size_t)sv * 4 + g];
            float e = (q < deg) ? lrelu(asg + ad_g) : -1e30f;
            float m = e;
            m = fmaxf(m, __shfl_xor(m, 1));
            m = fmaxf(m, __shfl_xor(m, 2));
            m = fmaxf(m, __shfl_xor(m, 4));
            m = fmaxf(m, __shfl_xor(m, 8));
            m = fmaxf(m, es);
            float wgt = (q < deg) ? __expf(e - m) : 0.f;
            float den = wgt;
            den += __shfl_xor(den, 1);
            den += __shfl_xor(den, 2);
            den += __shfl_xor(den, 4);
            den += __shfl_xor(den, 8);
            float se = __expf(es - m);
            den += se;
            float rinv = 0.25f / (den + 1e-16f);
            float wf = wgt * rinv;
            float selfw = se * rinv;
            unsigned goff = (unsigned)(g * 128 + q * 8);
            int b48 = lane & 48;
            f32x2 a0 = {0.f, 0.f}, a1 = {0.f, 0.f}, a2 = {0.f, 0.f}, a3 = {0.f, 0.f};
            int j = 0;
            for (; j + 2 <= deg; j += 2) {
                int sA = __builtin_amdgcn_readlane(sv, j);
                int sB = __builtin_amdgcn_readlane(sv, j + 1);
                float alA = __shfl(wf, b48 + j);
                float alB = __shfl(wf, b48 + j + 1);
                uint2 vA = *(const uint2*)(xw_a8 + (((unsigned)sA) << 9) + goff);
                uint2 vB = *(const uint2*)(xw_a8 + (((unsigned)sB) << 9) + goff);
                f32x2 mA = {alA, alA}, mB = {alB, alB};
                a0 += __builtin_amdgcn_cvt_pk_f32_fp8((int)vA.x, false) * mA;
                a1 += __builtin_amdgcn_cvt_pk_f32_fp8((int)vA.x, true) * mA;
                a2 += __builtin_amdgcn_cvt_pk_f32_fp8((int)vA.y, false) * mA;
                a3 += __builtin_amdgcn_cvt_pk_f32_fp8((int)vA.y, true) * mA;
                a0 += __builtin_amdgcn_cvt_pk_f32_fp8((int)vB.x, false) * mB;
                a1 += __builtin_amdgcn_cvt_pk_f32_fp8((int)vB.x, true) * mB;
                a2 += __builtin_amdgcn_cvt_pk_f32_fp8((int)vB.y, false) * mB;
                a3 += __builtin_amdgcn_cvt_pk_f32_fp8((int)vB.y, true) * mB;
            }
            if (j < deg) {
                int sA = __builtin_amdgcn_readlane(sv, j);
                float alA = __shfl(wf, b48 + j);
                uint2 vA = *(const uint2*)(xw_a8 + (((unsigned)sA) << 9) + goff);
                f32x2 mA = {alA, alA};
                a0 += __builtin_amdgcn_cvt_pk_f32_fp8((int)vA.x, false) * mA;
                a1 += __builtin_amdgcn_cvt_pk_f32_fp8((int)vA.x, true) * mA;
                a2 += __builtin_amdgcn_cvt_pk_f32_fp8((int)vA.y, false) * mA;
                a3 += __builtin_amdgcn_cvt_pk_f32_fp8((int)vA.y, true) * mA;
            }
            {
                uint2 v = *(const uint2*)(xw_a8 + (((unsigned)d) << 9) + goff);
                f32x2 ms = {selfw, selfw};
                a0 += __builtin_amdgcn_cvt_pk_f32_fp8((int)v.x, false) * ms;
                a1 += __builtin_amdgcn_cvt_pk_f32_fp8((int)v.x, true) * ms;
                a2 += __builtin_amdgcn_cvt_pk_f32_fp8((int)v.y, false) * ms;
                a3 += __builtin_amdgcn_cvt_pk_f32_fp8((int)v.y, true) * ms;
            }
            float av[8] = {a0[0], a0[1], a1[0], a1[1], a2[0], a2[1], a3[0], a3[1]};
            #pragma unroll
            for (int k = 0; k < 8; k++) {
                av[k] += __shfl_xor(av[k], 16);
                av[k] += __shfl_xor(av[k], 32);
            }
            if (g == 0) {
                float4 b0 = *(const float4*)(ba + q * 8);
                float4 b1 = *(const float4*)(ba + q * 8 + 4);
                float bb[8] = {b0.x, b0.y, b0.z, b0.w, b1.x, b1.y, b1.z, b1.w};
                unsigned o[4];
                #pragma unroll
                for (int k = 0; k < 4; k++) {
                    float v0 = fmaxf(av[2 * k] + bb[2 * k], 0.f);
                    float v1 = fmaxf(av[2 * k + 1] + bb[2 * k + 1], 0.f);
                    o[k] = (unsigned)f2b(v0) | ((unsigned)f2b(v1) << 16);
                }
                *(uint4*)(xcomb + (size_t)d * 256 + 128 + q * 8) = make_uint4(o[0], o[1], o[2], o[3]);
            }
            return;
        }
        float4 ad4 = *(const float4*)(a_d + (size_t)d * 4);
        float4 asd = *(const float4*)(a_s + (size_t)d * 4);
        float es0 = lrelu(asd.x + ad4.x), es1 = lrelu(asd.y + ad4.y);
        float es2 = lrelu(asd.z + ad4.z), es3 = lrelu(asd.w + ad4.w);
        if (deg <= 64) {
            int sv = 0;
            float e0 = -1e30f, e1 = -1e30f, e2 = -1e30f, e3 = -1e30f;
            if (lane < deg) {
                sv = csr_g[base + lane];
                float4 s4 = *(const float4*)(a_s + (size_t)sv * 4);
                e0 = lrelu(s4.x + ad4.x); e1 = lrelu(s4.y + ad4.y);
                e2 = lrelu(s4.z + ad4.z); e3 = lrelu(s4.w + ad4.w);
            }
            float m0 = e0, m1 = e1, m2 = e2, m3 = e3;
            #pragma unroll
            for (int off = 1; off < 64; off <<= 1) {
                m0 = fmaxf(m0, __shfl_xor(m0, off));
                m1 = fmaxf(m1, __shfl_xor(m1, off));
                m2 = fmaxf(m2, __shfl_xor(m2, off));
                m3 = fmaxf(m3, __shfl_xor(m3, off));
            }
            m0 = fmaxf(m0, es0); m1 = fmaxf(m1, es1);
            m2 = fmaxf(m2, es2); m3 = fmaxf(m3, es3);
            float w0 = (lane < deg) ? __expf(e0 - m0) : 0.f;
            float w1 = (lane < deg) ? __expf(e1 - m1) : 0.f;
            float w2 = (lane < deg) ? __expf(e2 - m2) : 0.f;
            float w3 = (lane < deg) ? __expf(e3 - m3) : 0.f;
            float d0 = w0, d1 = w1, d2 = w2, d3 = w3;
            #pragma unroll
            for (int off = 1; off < 64; off <<= 1) {
                d0 += __shfl_xor(d0, off); d1 += __shfl_xor(d1, off);
                d2 += __shfl_xor(d2, off); d3 += __shfl_xor(d3, off);
            }
            d0 += __expf(es0 - m0); d1 += __expf(es1 - m1);
            d2 += __expf(es2 - m2); d3 += __expf(es3 - m3);
            float r0 = 0.25f / (d0 + 1e-16f), r1 = 0.25f / (d1 + 1e-16f);
            float r2 = 0.25f / (d2 + 1e-16f), r3 = 0.25f / (d3 + 1e-16f);
            w0 *= r0; w1 *= r1; w2 *= r2; w3 *= r3;
            float wsel = (g == 0) ? w0 : (g == 1) ? w1 : (g == 2) ? w2 : w3;
            float selfw = (g == 0) ? __expf(es0 - m0) * r0 : (g == 1) ? __expf(es1 - m1) * r1
                        : (g == 2) ? __expf(es2 - m2) * r2 : __expf(es3 - m3) * r3;
            unsigned goff = (unsigned)(g * 128 + q * 8);
            f32x2 a0 = {0.f, 0.f}, a1 = {0.f, 0.f}, a2 = {0.f, 0.f}, a3 = {0.f, 0.f};
            for (int j = 0; j < deg; j++) {
                int s = __builtin_amdgcn_readlane(sv, j);
                float al = rdlane_f(wsel, j);
                uint2 v = *(const uint2*)(xw_a8 + (((unsigned)s) << 9) + goff);
                f32x2 mA = {al, al};
                a0 += __builtin_amdgcn_cvt_pk_f32_fp8((int)v.x, false) * mA;
                a1 += __builtin_amdgcn_cvt_pk_f32_fp8((int)v.x, true) * mA;
                a2 += __builtin_amdgcn_cvt_pk_f32_fp8((int)v.y, false) * mA;
                a3 += __builtin_amdgcn_cvt_pk_f32_fp8((int)v.y, true) * mA;
            }
            {
                uint2 v = *(const uint2*)(xw_a8 + (((unsigned)d) << 9) + goff);
                f32x2 ms = {selfw, selfw};
                a0 += __builtin_amdgcn_cvt_pk_f32_fp8((int)v.x, false) * ms;
                a1 += __builtin_amdgcn_cvt_pk_f32_fp8((int)v.x, true) * ms;
                a2 += __builtin_amdgcn_cvt_pk_f32_fp8((int)v.y, false) * ms;
                a3 += __builtin_amdgcn_cvt_pk_f32_fp8((int)v.y, true) * ms;
            }
            float av[8] = {a0[0], a0[1], a1[0], a1[1], a2[0], a2[1], a3[0], a3[1]};
            #pragma unroll
            for (int k = 0; k < 8; k++) {
                av[k] += __shfl_xor(av[k], 16);
                av[k] += __shfl_xor(av[k], 32);
            }
            if (g == 0) {
                float4 b0 = *(const float4*)(ba + q * 8);
                float4 b1 = *(const float4*)(ba + q * 8 + 4);
                float bb[8] = {b0.x, b0.y, b0.z, b0.w, b1.x, b1.y, b1.z, b1.w};
                unsigned o[4];
                #pragma unroll
                for (int k = 0; k < 4; k++) {
                    float v0 = fmaxf(av[2 * k] + bb[2 * k], 0.f);
                    float v1 = fmaxf(av[2 * k + 1] + bb[2 * k + 1], 0.f);
                    o[k] = (unsigned)f2b(v0) | ((unsigned)f2b(v1) << 16);
                }
                *(uint4*)(xcomb + (size_t)d * 256 + 128 + q * 8) = make_uint4(o[0], o[1], o[2], o[3]);
            }
        } else {
            int c2 = lane * 2;
            const unsigned short* xa = (const unsigned short*)xw_a8;
            float m0 = es0, m1 = es1, m2 = es2, m3 = es3;
            for (int i = base; i < end; i += 64) {
                int c = min(64, end - i);
                float t0 = -1e30f, t1 = -1e30f, t2 = -1e30f, t3 = -1e30f;
                if (lane < c) {
                    int s = csr_g[i + lane];
                    float4 s4 = *(const float4*)(a_s + (size_t)s * 4);
                    t0 = lrelu(s4.x + ad4.x); t1 = lrelu(s4.y + ad4.y);
                    t2 = lrelu(s4.z + ad4.z); t3 = lrelu(s4.w + ad4.w);
                }
                m0 = fmaxf(m0, t0); m1 = fmaxf(m1, t1);
                m2 = fmaxf(m2, t2); m3 = fmaxf(m3, t3);
            }
            #pragma unroll
            for (int off = 1; off < 64; off <<= 1) {
                m0 = fmaxf(m0, __shfl_xor(m0, off));
                m1 = fmaxf(m1, __shfl_xor(m1, off));
                m2 = fmaxf(m2, __shfl_xor(m2, off));
                m3 = fmaxf(m3, __shfl_xor(m3, off));
            }
            float d0 = 0.f, d1 = 0.f, d2 = 0.f, d3 = 0.f;
            for (int i = base; i < end; i += 64) {
                int c = min(64, end - i);
                if (lane < c) {
                    int s = csr_g[i + lane];
                    float4 s4 = *(const float4*)(a_s + (size_t)s * 4);
                    d0 += __expf(lrelu(s4.x + ad4.x) - m0);
                    d1 += __expf(lrelu(s4.y + ad4.y) - m1);
                    d2 += __expf(lrelu(s4.z + ad4.z) - m2);
                    d3 += __expf(lrelu(s4.w + ad4.w) - m3);
                }
            }
            #pragma unroll
            for (int off = 1; off < 64; off <<= 1) {
                d0 += __shfl_xor(d0, off); d1 += __shfl_xor(d1, off);
                d2 += __shfl_xor(d2, off); d3 += __shfl_xor(d3, off);
            }
            d0 += __expf(es0 - m0); d1 += __expf(es1 - m1);
            d2 += __expf(es2 - m2); d3 += __expf(es3 - m3);
            float r0 = 1.f / (d0 + 1e-16f), r1 = 1.f / (d1 + 1e-16f);
            float r2 = 1.f / (d2 + 1e-16f), r3 = 1.f / (d3 + 1e-16f);
            float ax = 0.f, ay = 0.f;
            for (int i = base; i < end; i += 64) {
                int c = min(64, end - i);
                int sv = 0;
                float w0 = 0.f, w1 = 0.f, w2 = 0.f, w3 = 0.f;
                if (lane < c) {
                    sv = csr_g[i + lane];
                    float4 s4 = *(const float4*)(a_s + (size_t)sv * 4);
                    w0 = __expf(lrelu(s4.x + ad4.x) - m0) * r0;
                    w1 = __expf(lrelu(s4.y + ad4.y) - m1) * r1;
                    w2 = __expf(lrelu(s4.z + ad4.z) - m2) * r2;
                    w3 = __expf(lrelu(s4.w + ad4.w) - m3) * r3;
                }
                for (int j = 0; j < c; j++) {
                    int s = __shfl(sv, j);
                    float a0 = __shfl(w0, j), a1 = __shfl(w1, j);
                    float a2 = __shfl(w2, j), a3 = __shfl(w3, j);
                    const unsigned short* row = xa + (size_t)s * 256 + lane;
                    f32x2 v0 = fp8x2_to_f32(row[0]);
                    f32x2 v1 = fp8x2_to_f32(row[64]);
                    f32x2 v2 = fp8x2_to_f32(row[128]);
                    f32x2 v3 = fp8x2_to_f32(row[192]);
                    ax = fmaf(v0[0], a0, ax); ay = fmaf(v0[1], a0, ay);
                    ax = fmaf(v1[0], a1, ax); ay = fmaf(v1[1], a1, ay);
                    ax = fmaf(v2[0], a2, ax); ay = fmaf(v2[1], a2, ay);
                    ax = fmaf(v3[0], a3, ax); ay = fmaf(v3[1], a3, ay);
                }
            }
            float s0 = __expf(es0 - m0) * r0, s1 = __expf(es1 - m1) * r1;
            float s2 = __expf(es2 - m2) * r2, s3 = __expf(es3 - m3) * r3;
            const unsigned short* row = xa + (size_t)d * 256 + lane;
            f32x2 v0 = fp8x2_to_f32(row[0]);
            f32x2 v1 = fp8x2_to_f32(row[64]);
            f32x2 v2 = fp8x2_to_f32(row[128]);
            f32x2 v3 = fp8x2_to_f32(row[192]);
            ax = fmaf(v0[0], s0, ax); ay = fmaf(v0[1], s0, ay);
            ax = fmaf(v1[0], s1, ax); ay = fmaf(v1[1], s1, ay);
            ax = fmaf(v2[0], s2, ax); ay = fmaf(v2[1], s2, ay);
            ax = fmaf(v3[0], s3, ax); ay = fmaf(v3[1], s3, ay);
            float ox = fmaxf(0.25f * ax + ba[c2], 0.f);
            float oy = fmaxf(0.25f * ay + ba[c2 + 1], 0.f);
            unsigned uo = (unsigned)f2b(ox) | ((unsigned)f2b(oy) << 16);
            *(unsigned*)(xcomb + (size_t)d * 256 + 128 + c2) = uo;
        }
    }
}

// ---------- D6: pooled GEMM + column-mean; last block computes the heads ----------
__global__ __launch_bounds__(256) void mfma_pool_head(
    const unsigned short* __restrict__ A, const unsigned short* __restrict__ Bt,
    const float* __restrict__ bp, float* __restrict__ sumvec, int* __restrict__ counter,
    int M,
    const float* __restrict__ Wc1, const float* __restrict__ bc1,
    const float* __restrict__ Wc2, const float* __restrict__ bc2,
    const float* __restrict__ Wu, const float* __restrict__ bu,
    float* __restrict__ out)
{
    __shared__ unsigned short As[128 * 128];
    __shared__ unsigned short Bs[128 * 128];
    __shared__ float red[128];
    __shared__ int lastflag;
    int tid = threadIdx.x;
    int lane = tid & 63, w = tid >> 6;
    int wr = w >> 1, wc = w & 1;
    int l16 = lane & 15, lhi = lane >> 4;
    int m0 = blockIdx.x * 128;
    f32x4 acc[4][4] = {};
    for (int kb = 0; kb < 256; kb += 128) {
        if (kb) __syncthreads();
        #pragma unroll
        for (int i = 0; i < 8; i++) {
            int u = tid + i * 256;
            int row = u >> 4, e0 = (u & 15) << 3;
            int sw = e0 ^ ((row & 7) << 3);
            bf16x8 va = {};
            int gr = m0 + row;
            if (gr < M) va = *(const bf16x8*)(A + (size_t)gr * 256 + kb + e0);
            *(bf16x8*)(As + row * 128 + sw) = va;
            bf16x8 vb = *(const bf16x8*)(Bt + (size_t)row * 256 + kb + e0);
            *(bf16x8*)(Bs + row * 128 + sw) = vb;
        }
        __syncthreads();
        #pragma unroll
        for (int kk = 0; kk < 4; kk++) {
            int ke = kk * 32 + lhi * 8;
            bf16x8 af[4], bfr[4];
            #pragma unroll
            for (int m = 0; m < 4; m++) {
                int r = wr * 64 + m * 16 + l16;
                af[m] = *(const bf16x8*)(As + r * 128 + (ke ^ ((r & 7) << 3)));
            }
            #pragma unroll
            for (int n = 0; n < 4; n++) {
                int r = wc * 64 + n * 16 + l16;
                bfr[n] = *(const bf16x8*)(Bs + r * 128 + (ke ^ ((r & 7) << 3)));
            }
            #pragma unroll
            for (int m = 0; m < 4; m++)
                #pragma unroll
                for (int n = 0; n < 4; n++)
                    acc[m][n] = __builtin_amdgcn_mfma_f32_16x16x32_bf16(af[m], bfr[n], acc[m][n], 0, 0, 0);
        }
    }
    float bcol[4];
    #pragma unroll
    for (int n = 0; n < 4; n++) bcol[n] = bp[wc * 64 + n * 16 + l16];
    float colsum[4] = {0.f, 0.f, 0.f, 0.f};
    #pragma unroll
    for (int m = 0; m < 4; m++) {
        #pragma unroll
        for (int r = 0; r < 4; r++) {
            int row_g = m0 + wr * 64 + m * 16 + lhi * 4 + r;
            if (row_g < M) {
                #pragma unroll
                for (int n = 0; n < 4; n++)
                    colsum[n] += fmaxf(acc[m][n][r] + bcol[n], 0.f);
            }
        }
    }
    #pragma unroll
    for (int n = 0; n < 4; n++) {
        colsum[n] += __shfl_xor(colsum[n], 16);
        colsum[n] += __shfl_xor(colsum[n], 32);
    }
    if (tid < 128) red[tid] = 0.f;
    __syncthreads();
    if (lhi == 0) {
        #pragma unroll
        for (int n = 0; n < 4; n++)
            atomicAdd(&red[wc * 64 + n * 16 + l16], colsum[n]);
    }
    __syncthreads();
    if (tid < 128) atomicAdd(&sumvec[tid], red[tid]);
    // ---- last-block heads epilogue ----
    __threadfence();
    __syncthreads();
    if (tid == 0) lastflag = (atomicAdd(counter, 1) == (int)gridDim.x - 1);
    __syncthreads();
    if (!lastflag) return;
    __shared__ float xf[128];
    __shared__ float h1[64];
    if (tid < 128) xf[tid] = atomicAdd(&sumvec[tid], 0.f) * (1.0f / N_NODES);
    __syncthreads();
    if (tid < 64) {
        float s = bc1[tid];
        for (int c = 0; c < 128; c++) s = fmaf(xf[c], Wc1[c * 64 + tid], s);
        h1[tid] = fmaxf(s, 0.f);
    }
    __syncthreads();
    if (tid < 16) {
        float s = bc2[tid];
        for (int j = 0; j < 64; j++) s = fmaf(h1[j], Wc2[j * 16 + tid], s);
        out[tid] = s;
        float u = bu[tid];
        for (int c = 0; c < 128; c++) u = fmaf(xf[c], Wu[c * 16 + tid], u);
        out[16 + tid] = 1.0f / (1.0f + expf(-u));
    }
}

extern "C" void kernel_launch(void* const* d_in, const int* in_sizes, int n_in,
                              void* d_out, int out_size, void* d_ws, size_t ws_size,
                              hipStream_t stream) {
    const float* x    = (const float*)d_in[0];
    const int*   lei  = (const int*)d_in[1];
    const int*   gei  = (const int*)d_in[2];
    const float* W1   = (const float*)d_in[3];
    const float* b1   = (const float*)d_in[4];
    const float* Wg   = (const float*)d_in[5];
    const float* bg   = (const float*)d_in[6];
    const float* Wa   = (const float*)d_in[7];
    const float* atts = (const float*)d_in[8];
    const float* attd = (const float*)d_in[9];
    const float* ba   = (const float*)d_in[10];
    const float* Wp   = (const float*)d_in[11];
    const float* bp   = (const float*)d_in[12];
    const float* Wc1  = (const float*)d_in[13];
    const float* bc1  = (const float*)d_in[14];
    const float* Wc2  = (const float*)d_in[15];
    const float* bc2  = (const float*)d_in[16];
    const float* Wu   = (const float*)d_in[17];
    const float* bu   = (const float*)d_in[18];

    const int* lsrc = lei;
    const int* ldst = lei + EL;
    const int* gsrc = gei;
    const int* gdst = gei + EG;

    uintptr_t base = (uintptr_t)d_ws;
    auto alloc = [&](size_t bytes) { void* p = (void*)base; base += (bytes + 255) & ~(size_t)255; return p; };
    unsigned short* x_loc  = (unsigned short*)alloc((size_t)N_NODES * 128 * 2);
    unsigned char*  xw_g8  = (unsigned char*)alloc((size_t)N_NODES * 128);
    unsigned char*  xw_a8  = (unsigned char*)alloc((size_t)N_NODES * 512);
    unsigned short* xcomb  = (unsigned short*)alloc((size_t)N_NODES * 256 * 2);
    unsigned short* W1t    = (unsigned short*)alloc((size_t)128 * 128 * 2);
    unsigned short* Wgt    = (unsigned short*)alloc((size_t)128 * 128 * 2);
    unsigned short* Wat    = (unsigned short*)alloc((size_t)512 * 128 * 2);
    unsigned short* Wpt    = (unsigned short*)alloc((size_t)128 * 256 * 2);
    float* dinv       = (float*)alloc((size_t)N_NODES * 4);
    float* a_s        = (float*)alloc((size_t)N_NODES * 4 * 4);
    float* a_d        = (float*)alloc((size_t)N_NODES * 4 * 4);
    int*   ghist      = (int*)alloc((size_t)2 * NB * 4);
    int*   bbase      = (int*)alloc((size_t)2 * (NB + 1) * 4);
    int*   gcur       = (int*)alloc((size_t)2 * NB * 4);
    unsigned* ebuf_l  = (unsigned*)alloc((size_t)EL * 4);
    unsigned* ebuf_g  = (unsigned*)alloc((size_t)EG * 4);
    int*   offs_l     = (int*)alloc(((size_t)N_NODES + 1) * 4);
    int*   offs_g     = (int*)alloc(((size_t)N_NODES + 1) * 4);
    unsigned short* csr_l = (unsigned short*)alloc((size_t)EL * 2);
    unsigned short* csr_g = (unsigned short*)alloc((size_t)EG * 2);
    float* sumvec     = (float*)alloc(128 * 4 + 256);
    int*   counter    = (int*)(sumvec + 128);

    hipMemsetAsync(ghist, 0, (size_t)2 * NB * 4, stream);
    hipMemsetAsync(sumvec, 0, 128 * 4 + 4, stream);   // sumvec + counter

    // D1: weights -> bf16^T + bucket histogram
    conv_hist<<<757, 256, 0, stream>>>(W1, W1t, Wg, Wgt, Wa, Wat, Wp, Wpt,
                                       ldst, gdst, ghist);
    // D2: bucket scan (2 blocks) || x_local GEMM (391 blocks)
    scan_gemmx<<<393, 256, 0, stream>>>(ghist, bbase, gcur, x, W1t, b1, x_loc, N_NODES);
    // D3: Wg+Wa GEMMs (391 blocks) || edge partition (245 blocks)
    part_gw5<<<GB + 245, 256, 0, stream>>>(x_loc, Wgt, Wat, xw_g8, xw_a8, N_NODES,
                                           atts, attd, a_s, a_d,
                                           lsrc, ldst, gsrc, gdst, gcur, ebuf_l, ebuf_g);
    // D4: per-bucket CSR + dinv + xw_g8 rescale
    bucket_csr<<<392, 256, 0, stream>>>(ebuf_l, ebuf_g, bbase, offs_l, offs_g,
                                        csr_l, csr_g, dinv, (unsigned*)xw_g8);
    // D5: both gathers
    fused_gather<<<25000, 256, 0, stream>>>(offs_l, csr_l, xw_g8, dinv, bg,
                                            offs_g, csr_g, a_s, a_d, xw_a8, ba, xcomb);
    // D6: pool + heads (last-block epilogue)
    mfma_pool_head<<<GB, 256, 0, stream>>>(xcomb, Wpt, bp, sumvec, counter, N_NODES,
                                           Wc1, bc1, Wc2, bc2, Wu, bu, (float*)d_out);
}

// Round 13
// 187.212 us; speedup vs baseline: 1.1039x; 1.1039x over previous
//
#include <hip/hip_runtime.h>
#include <hip/hip_bf16.h>

#define N_NODES 50000
#define F_IN 128
#define HID 128
#define N_OUT 16
#define HEADS 4
#define EL 800000
#define EG 200000
#define NEG_SLOPE 0.2f
#define NB 196    // buckets of 256 nodes
#define GB 391    // ceil(50000/128)

typedef short bf16x8 __attribute__((ext_vector_type(8)));
typedef float f32x4 __attribute__((ext_vector_type(4)));
typedef float f32x2 __attribute__((ext_vector_type(2)));

static __device__ __forceinline__ float lrelu(float x) {
    return x > 0.f ? x : NEG_SLOPE * x;
}
static __device__ __forceinline__ unsigned short f2b(float f) {
    __hip_bfloat16 h = __float2bfloat16(f);
    return *reinterpret_cast<unsigned short*>(&h);
}
static __device__ __forceinline__ unsigned char f2fp8(float f) {
    unsigned pk = __builtin_amdgcn_cvt_pk_fp8_f32(f, f, 0, false);
    return (unsigned char)(pk & 0xFF);
}
static __device__ __forceinline__ f32x2 fp8x2_to_f32(unsigned u) {
    return __builtin_amdgcn_cvt_pk_f32_fp8((int)u, false);
}
static __device__ __forceinline__ float rdlane_f(float v, int l) {
    return __int_as_float(__builtin_amdgcn_readlane(__float_as_int(v), l));
}

// ---------- D1: weight conversions + bucket histogram ----------
__global__ __launch_bounds__(256) void conv_hist(
    const float* __restrict__ W1, unsigned short* __restrict__ W1t,
    const float* __restrict__ Wg, unsigned short* __restrict__ Wgt,
    const float* __restrict__ Wa, unsigned short* __restrict__ Wat,
    const float* __restrict__ Wp, unsigned short* __restrict__ Wpt,
    const int* __restrict__ ldst, const int* __restrict__ gdst, int* __restrict__ ghist)
{
    int b = blockIdx.x, t = threadIdx.x;
    if (b < 64) {                         // W1 [128][128] -> [n][k]
        int idx = b * 256 + t;
        int k = idx >> 7, n = idx & 127;
        W1t[n * 128 + k] = f2b(W1[idx]);
    } else if (b < 128) {                 // Wg
        int idx = (b - 64) * 256 + t;
        int k = idx >> 7, n = idx & 127;
        Wgt[n * 128 + k] = f2b(Wg[idx]);
    } else if (b < 384) {                 // Wa [128][512] -> [512][128]
        int idx = (b - 128) * 256 + t;
        int k = idx >> 9, n = idx & 511;
        Wat[(size_t)n * 128 + k] = f2b(Wa[idx]);
    } else if (b < 512) {                 // Wp [256][128] -> [128][256]
        int idx = (b - 384) * 256 + t;
        int k = idx >> 7, n = idx & 127;
        Wpt[(size_t)n * 256 + k] = f2b(Wp[idx]);
    } else {                              // bucket histogram
        __shared__ int lh[NB];
        int blk = b - 512;
        bool loc = blk < 196;
        const int* dstp = loc ? ldst : gdst;
        int nE = loc ? EL : EG;
        int* gh = ghist + (loc ? 0 : NB);
        int start = (loc ? blk : blk - 196) * 4096;
        if (t < NB) lh[t] = 0;
        __syncthreads();
        #pragma unroll
        for (int i = 0; i < 16; i++) {
            int e = start + i * 256 + t;
            if (e < nE) atomicAdd(&lh[dstp[e] >> 8], 1);
        }
        __syncthreads();
        if (t < NB && lh[t]) atomicAdd(&gh[t], lh[t]);
    }
}

// ---------- D2: bucket scan (blocks 0-1) + gemm_x (blocks 2..392) ----------
__global__ __launch_bounds__(256) void scan_gemmx(
    const int* __restrict__ ghist, int* __restrict__ bbase, int* __restrict__ gcur,
    const float* __restrict__ A, const unsigned short* __restrict__ Bt,
    const float* __restrict__ bias, unsigned short* __restrict__ out, int M)
{
    __shared__ unsigned short As[128 * 128];
    __shared__ unsigned short Bs[128 * 128];
    int tid = threadIdx.x;
    if (blockIdx.x < 2) {
        int* s = (int*)As;
        int g = blockIdx.x, t = tid;
        int v = (t < NB) ? ghist[g * NB + t] : 0;
        s[t] = v;
        __syncthreads();
        for (int off = 1; off < 256; off <<= 1) {
            int u = (t >= off) ? s[t - off] : 0;
            __syncthreads();
            s[t] += u;
            __syncthreads();
        }
        if (t < NB) {
            bbase[g * (NB + 1) + t] = s[t] - v;
            gcur[g * NB + t] = s[t] - v;
        }
        if (t == NB - 1) bbase[g * (NB + 1) + NB] = s[t];
        return;
    }
    int lane = tid & 63, w = tid >> 6;
    int wr = w >> 1, wc = w & 1;
    int l16 = lane & 15, lhi = lane >> 4;
    int m0 = (blockIdx.x - 2) * 128;
    f32x4 acc[4][4] = {};
    #pragma unroll
    for (int i = 0; i < 8; i++) {
        int u = tid + i * 256;
        int row = u >> 4, e0 = (u & 15) << 3;
        int sw = e0 ^ ((row & 7) << 3);
        int gr = m0 + row;
        unsigned short pb[8] = {};
        if (gr < M) {
            float4 a0 = *(const float4*)(A + (size_t)gr * 128 + e0);
            float4 a1 = *(const float4*)(A + (size_t)gr * 128 + e0 + 4);
            pb[0] = f2b(a0.x); pb[1] = f2b(a0.y); pb[2] = f2b(a0.z); pb[3] = f2b(a0.w);
            pb[4] = f2b(a1.x); pb[5] = f2b(a1.y); pb[6] = f2b(a1.z); pb[7] = f2b(a1.w);
        }
        *(bf16x8*)(As + row * 128 + sw) = *(bf16x8*)pb;
        bf16x8 vb = *(const bf16x8*)(Bt + (size_t)row * 128 + e0);
        *(bf16x8*)(Bs + row * 128 + sw) = vb;
    }
    __syncthreads();
    #pragma unroll
    for (int kk = 0; kk < 4; kk++) {
        int ke = kk * 32 + lhi * 8;
        bf16x8 af[4], bfr[4];
        #pragma unroll
        for (int m = 0; m < 4; m++) {
            int r = wr * 64 + m * 16 + l16;
            af[m] = *(const bf16x8*)(As + r * 128 + (ke ^ ((r & 7) << 3)));
        }
        #pragma unroll
        for (int n = 0; n < 4; n++) {
            int r = wc * 64 + n * 16 + l16;
            bfr[n] = *(const bf16x8*)(Bs + r * 128 + (ke ^ ((r & 7) << 3)));
        }
        #pragma unroll
        for (int m = 0; m < 4; m++)
            #pragma unroll
            for (int n = 0; n < 4; n++)
                acc[m][n] = __builtin_amdgcn_mfma_f32_16x16x32_bf16(af[m], bfr[n], acc[m][n], 0, 0, 0);
    }
    #pragma unroll
    for (int m = 0; m < 4; m++) {
        #pragma unroll
        for (int r = 0; r < 4; r++) {
            int row_g = m0 + wr * 64 + m * 16 + lhi * 4 + r;
            if (row_g >= M) continue;
            #pragma unroll
            for (int n = 0; n < 4; n++) {
                int col_g = wc * 64 + n * 16 + l16;
                float v = fmaxf(acc[m][n][r] + bias[col_g], 0.f);
                out[(size_t)row_g * 128 + col_g] = f2b(v);
            }
        }
    }
}

// ---------- D3: edge partition into bucket-contiguous ebuf (lean kernel) ----------
__global__ __launch_bounds__(256) void bucket_part(
    const int* __restrict__ lsrc, const int* __restrict__ ldst,
    const int* __restrict__ gsrc, const int* __restrict__ gdst,
    int* __restrict__ gcur, unsigned* __restrict__ ebuf_l, unsigned* __restrict__ ebuf_g)
{
    __shared__ int lhist[NB], lbase[NB];
    int blk = blockIdx.x, t = threadIdx.x;
    bool loc = blk < 196;
    const int* srcp = loc ? lsrc : gsrc;
    const int* dstp = loc ? ldst : gdst;
    int nE = loc ? EL : EG;
    unsigned* ebuf = loc ? ebuf_l : ebuf_g;
    int* cur = gcur + (loc ? 0 : NB);
    int start = (loc ? blk : blk - 196) * 4096;
    if (t < NB) lhist[t] = 0;
    __syncthreads();
    unsigned pk[16];
    #pragma unroll
    for (int i = 0; i < 16; i++) {
        int e = start + i * 256 + t;
        if (e < nE) {
            unsigned d = (unsigned)dstp[e];
            pk[i] = (d << 16) | (unsigned)srcp[e];
            atomicAdd(&lhist[d >> 8], 1);
        } else pk[i] = 0xFFFFFFFFu;
    }
    __syncthreads();
    if (t < NB) lbase[t] = atomicAdd(&cur[t], lhist[t]);
    __syncthreads();
    if (t < NB) lhist[t] = 0;
    __syncthreads();
    #pragma unroll
    for (int i = 0; i < 16; i++) {
        unsigned b = pk[i] >> 24;
        if (b < NB) {
            int r = atomicAdd(&lhist[b], 1);
            ebuf[lbase[b] + r] = pk[i];
        }
    }
}

// ---------- D4: per-bucket fine CSR + dinv ----------
__global__ __launch_bounds__(256) void bucket_csr(
    const unsigned* __restrict__ ebuf_l, const unsigned* __restrict__ ebuf_g,
    const int* __restrict__ bbase,
    int* __restrict__ offs_l, int* __restrict__ offs_g,
    unsigned short* __restrict__ csr_l, unsigned short* __restrict__ csr_g,
    float* __restrict__ dinv)
{
    __shared__ int cnt[256], s[256], cur[256];
    int blk = blockIdx.x, t = threadIdx.x;
    bool loc = blk < 196;
    int b = loc ? blk : blk - 196;
    const unsigned* ebuf = loc ? ebuf_l : ebuf_g;
    const int* bb = bbase + (loc ? 0 : NB + 1);
    int* offs = loc ? offs_l : offs_g;
    unsigned short* csr = loc ? csr_l : csr_g;
    int rs = bb[b], re = bb[b + 1];
    cnt[t] = 0;
    __syncthreads();
    for (int i = rs + t; i < re; i += 256) atomicAdd(&cnt[(ebuf[i] >> 16) & 255], 1);
    __syncthreads();
    int v = cnt[t];
    s[t] = v;
    __syncthreads();
    for (int off = 1; off < 256; off <<= 1) {
        int u = (t >= off) ? s[t - off] : 0;
        __syncthreads();
        s[t] += u;
        __syncthreads();
    }
    int excl = s[t] - v;
    int node = b * 256 + t;
    cur[t] = rs + excl;
    if (node < N_NODES) {
        offs[node] = rs + excl;
        if (loc) dinv[node] = rsqrtf((float)(v + 1));
    }
    if (blk == 0 && t == 0) offs_l[N_NODES] = EL;
    if (blk == 196 && t == 0) offs_g[N_NODES] = EG;
    __syncthreads();
    for (int i = rs + t; i < re; i += 256) {
        unsigned pk = ebuf[i];
        int r = atomicAdd(&cur[(pk >> 16) & 255], 1);
        csr[r] = (unsigned short)(pk & 0xFFFFu);
    }
}

// ---------- D5: Wg + 4×Wa GEMMs, A staged once; xw_g pre-scaled by dinv ----------
__global__ __launch_bounds__(256) void gemm_gw5(
    const unsigned short* __restrict__ A, const unsigned short* __restrict__ Wgt,
    const unsigned short* __restrict__ Wat,
    unsigned char* __restrict__ xw_g8, unsigned char* __restrict__ xw_a8, int M,
    const float* __restrict__ atts, const float* __restrict__ attd,
    float* __restrict__ a_s, float* __restrict__ a_d,
    const float* __restrict__ dinv)
{
    __shared__ unsigned short As[128 * 128];
    __shared__ unsigned short Bs[128 * 128];
    __shared__ float sas[128], sad[128];
    int tid = threadIdx.x;
    int lane = tid & 63, w = tid >> 6;
    int wr = w >> 1, wc = w & 1;
    int l16 = lane & 15, lhi = lane >> 4;
    int m0 = blockIdx.x * 128;
    #pragma unroll
    for (int i = 0; i < 8; i++) {
        int u = tid + i * 256;
        int row = u >> 4, e0 = (u & 15) << 3;
        int sw = e0 ^ ((row & 7) << 3);
        bf16x8 va = {};
        int gr = m0 + row;
        if (gr < M) va = *(const bf16x8*)(A + (size_t)gr * 128 + e0);
        *(bf16x8*)(As + row * 128 + sw) = va;
    }
    for (int p = 0; p < 5; p++) {
        const unsigned short* Bt = (p == 0) ? Wgt : (Wat + (size_t)(p - 1) * 128 * 128);
        __syncthreads();
        #pragma unroll
        for (int i = 0; i < 8; i++) {
            int u = tid + i * 256;
            int row = u >> 4, e0 = (u & 15) << 3;
            int sw = e0 ^ ((row & 7) << 3);
            bf16x8 vb = *(const bf16x8*)(Bt + (size_t)row * 128 + e0);
            *(bf16x8*)(Bs + row * 128 + sw) = vb;
        }
        if (tid < 128) { sas[tid] = 0.f; sad[tid] = 0.f; }
        __syncthreads();
        f32x4 acc[4][4] = {};
        #pragma unroll
        for (int kk = 0; kk < 4; kk++) {
            int ke = kk * 32 + lhi * 8;
            bf16x8 af[4], bfr[4];
            #pragma unroll
            for (int m = 0; m < 4; m++) {
                int r = wr * 64 + m * 16 + l16;
                af[m] = *(const bf16x8*)(As + r * 128 + (ke ^ ((r & 7) << 3)));
            }
            #pragma unroll
            for (int n = 0; n < 4; n++) {
                int r = wc * 64 + n * 16 + l16;
                bfr[n] = *(const bf16x8*)(Bs + r * 128 + (ke ^ ((r & 7) << 3)));
            }
            #pragma unroll
            for (int m = 0; m < 4; m++)
                #pragma unroll
                for (int n = 0; n < 4; n++)
                    acc[m][n] = __builtin_amdgcn_mfma_f32_16x16x32_bf16(af[m], bfr[n], acc[m][n], 0, 0, 0);
        }
        if (p == 0) {
            #pragma unroll
            for (int m = 0; m < 4; m++)
                #pragma unroll
                for (int r = 0; r < 4; r++) {
                    int row_g = m0 + wr * 64 + m * 16 + lhi * 4 + r;
                    if (row_g >= M) continue;
                    float dv = dinv[row_g];
                    #pragma unroll
                    for (int n = 0; n < 4; n++) {
                        int col_g = wc * 64 + n * 16 + l16;
                        xw_g8[(size_t)row_g * 128 + col_g] = f2fp8(acc[m][n][r] * dv);
                    }
                }
        } else {
            int head = p - 1;
            float ats[4], atd[4];
            #pragma unroll
            for (int n = 0; n < 4; n++) {
                int cl = wc * 64 + n * 16 + l16;
                ats[n] = atts[head * 128 + cl];
                atd[n] = attd[head * 128 + cl];
            }
            #pragma unroll
            for (int m = 0; m < 4; m++) {
                #pragma unroll
                for (int r = 0; r < 4; r++) {
                    int row_l = wr * 64 + m * 16 + lhi * 4 + r;
                    int row_g = m0 + row_l;
                    float ps = 0.f, pd = 0.f;
                    #pragma unroll
                    for (int n = 0; n < 4; n++) {
                        float v = acc[m][n][r];
                        ps = fmaf(v, ats[n], ps);
                        pd = fmaf(v, atd[n], pd);
                        if (row_g < M) {
                            int col_g = head * 128 + wc * 64 + n * 16 + l16;
                            xw_a8[(size_t)row_g * 512 + col_g] = f2fp8(v);
                        }
                    }
                    #pragma unroll
                    for (int off = 1; off < 16; off <<= 1) {
                        ps += __shfl_xor(ps, off);
                        pd += __shfl_xor(pd, off);
                    }
                    if (l16 == 0) {
                        atomicAdd(&sas[row_l], ps);
                        atomicAdd(&sad[row_l], pd);
                    }
                }
            }
            __syncthreads();
            if (tid < 128) {
                int row_g = m0 + tid;
                if (row_g < M) {
                    a_s[(size_t)row_g * 4 + head] = sas[tid];
                    a_d[(size_t)row_g * 4 + head] = sad[tid];
                }
            }
        }
    }
}

// ---------- D6: fused gathers ----------
__global__ __launch_bounds__(256) void fused_gather(
    const int* __restrict__ offs_l, const unsigned short* __restrict__ csr_l,
    const unsigned char* __restrict__ xw_g8, const float* __restrict__ dinv,
    const float* __restrict__ bg,
    const int* __restrict__ offs_g, const unsigned short* __restrict__ csr_g,
    const float* __restrict__ a_s, const float* __restrict__ a_d,
    const unsigned char* __restrict__ xw_a8, const float* __restrict__ ba,
    unsigned short* __restrict__ xcomb)
{
    int blk = blockIdx.x;
    int tid = threadIdx.x;
    int lane = tid & 63;
    int g = lane >> 4, q = lane & 15;
    if (blk < 12500) {
        int d = (blk * 256 + tid) >> 6;
        if (d >= N_NODES) return;
        int base = offs_l[d], end = offs_l[d + 1];
        unsigned goff = (unsigned)q * 8u;
        f32x2 a0 = {0.f, 0.f}, a1 = {0.f, 0.f}, a2 = {0.f, 0.f}, a3 = {0.f, 0.f};
        for (int i = base; i < end; ) {
            int chunk = min(64, end - i);
            int sv = (lane < chunk) ? (int)csr_l[i + lane] : 0;
            int nst = (chunk + 3) >> 2;
            int j = 0;
            for (; j + 2 <= nst; j += 2) {
                int eA = j * 4 + g, eB = eA + 4;
                int sA = __shfl(sv, eA);
                int sB = __shfl(sv, eB);
                float mkA = (eA < chunk) ? 1.f : 0.f;
                float mkB = (eB < chunk) ? 1.f : 0.f;
                uint2 vA = *(const uint2*)(xw_g8 + (((unsigned)sA) << 7) + goff);
                uint2 vB = *(const uint2*)(xw_g8 + (((unsigned)sB) << 7) + goff);
                f32x2 mA = {mkA, mkA}, mB = {mkB, mkB};
                a0 += __builtin_amdgcn_cvt_pk_f32_fp8((int)vA.x, false) * mA;
                a1 += __builtin_amdgcn_cvt_pk_f32_fp8((int)vA.x, true) * mA;
                a2 += __builtin_amdgcn_cvt_pk_f32_fp8((int)vA.y, false) * mA;
                a3 += __builtin_amdgcn_cvt_pk_f32_fp8((int)vA.y, true) * mA;
                a0 += __builtin_amdgcn_cvt_pk_f32_fp8((int)vB.x, false) * mB;
                a1 += __builtin_amdgcn_cvt_pk_f32_fp8((int)vB.x, true) * mB;
                a2 += __builtin_amdgcn_cvt_pk_f32_fp8((int)vB.y, false) * mB;
                a3 += __builtin_amdgcn_cvt_pk_f32_fp8((int)vB.y, true) * mB;
            }
            for (; j < nst; j++) {
                int e = j * 4 + g;
                int s = __shfl(sv, e);
                float mk = (e < chunk) ? 1.f : 0.f;
                f32x2 m2 = {mk, mk};
                uint2 v = *(const uint2*)(xw_g8 + (((unsigned)s) << 7) + goff);
                a0 += __builtin_amdgcn_cvt_pk_f32_fp8((int)v.x, false) * m2;
                a1 += __builtin_amdgcn_cvt_pk_f32_fp8((int)v.x, true) * m2;
                a2 += __builtin_amdgcn_cvt_pk_f32_fp8((int)v.y, false) * m2;
                a3 += __builtin_amdgcn_cvt_pk_f32_fp8((int)v.y, true) * m2;
            }
            i += chunk;
        }
        float av[8] = {a0[0], a0[1], a1[0], a1[1], a2[0], a2[1], a3[0], a3[1]};
        #pragma unroll
        for (int k = 0; k < 8; k++) {
            av[k] += __shfl_xor(av[k], 16);
            av[k] += __shfl_xor(av[k], 32);
        }
        if (g == 0) {
            float dd = dinv[d];
            uint2 sv2 = *(const uint2*)(xw_g8 + (((unsigned)d) << 7) + goff);
            f32x2 s0 = fp8x2_to_f32(sv2.x & 0xFFFFu);
            f32x2 s1 = __builtin_amdgcn_cvt_pk_f32_fp8((int)sv2.x, true);
            f32x2 s2 = fp8x2_to_f32(sv2.y & 0xFFFFu);
            f32x2 s3 = __builtin_amdgcn_cvt_pk_f32_fp8((int)sv2.y, true);
            float sf[8] = {s0[0], s0[1], s1[0], s1[1], s2[0], s2[1], s3[0], s3[1]};
            float4 b0 = *(const float4*)(bg + q * 8);
            float4 b1 = *(const float4*)(bg + q * 8 + 4);
            float bb[8] = {b0.x, b0.y, b0.z, b0.w, b1.x, b1.y, b1.z, b1.w};
            unsigned o[4];
            #pragma unroll
            for (int k = 0; k < 4; k++) {
                float v0 = fmaxf(dd * (av[2 * k] + sf[2 * k]) + bb[2 * k], 0.f);
                float v1 = fmaxf(dd * (av[2 * k + 1] + sf[2 * k + 1]) + bb[2 * k + 1], 0.f);
                o[k] = (unsigned)f2b(v0) | ((unsigned)f2b(v1) << 16);
            }
            *(uint4*)(xcomb + (size_t)d * 256 + q * 8) = make_uint4(o[0], o[1], o[2], o[3]);
        }
    } else {
        int d = ((blk - 12500) * 256 + tid) >> 6;
        if (d >= N_NODES) return;
        int base = offs_g[d], end = offs_g[d + 1];
        int deg = end - base;
        if (deg <= 16) {
            float ad_g = a_d[(size_t)d * 4 + g];
            float es = lrelu(a_s[(size_t)d * 4 + g] + ad_g);
            int sv = (q < deg) ? (int)csr_g[base + q] : 0;
            float asg = a_s[(size_t)sv * 4 + g];
            float e = (q < deg) ? lrelu(asg + ad_g) : -1e30f;
            float m = e;
            m = fmaxf(m, __shfl_xor(m, 1));
            m = fmaxf(m, __shfl_xor(m, 2));
            m = fmaxf(m, __shfl_xor(m, 4));
            m = fmaxf(m, __shfl_xor(m, 8));
            m = fmaxf(m, es);
            float wgt = (q < deg) ? __expf(e - m) : 0.f;
            float den = wgt;
            den += __shfl_xor(den, 1);
            den += __shfl_xor(den, 2);
            den += __shfl_xor(den, 4);
            den += __shfl_xor(den, 8);
            float se = __expf(es - m);
            den += se;
            float rinv = 0.25f / (den + 1e-16f);
            float wf = wgt * rinv;
            float selfw = se * rinv;
            unsigned goff = (unsigned)(g * 128 + q * 8);
            int b48 = lane & 48;
            f32x2 a0 = {0.f, 0.f}, a1 = {0.f, 0.f}, a2 = {0.f, 0.f}, a3 = {0.f, 0.f};
            int j = 0;
            for (; j + 2 <= deg; j += 2) {
                int sA = __builtin_amdgcn_readlane(sv, j);
                int sB = __builtin_amdgcn_readlane(sv, j + 1);
                float alA = __shfl(wf, b48 + j);
                float alB = __shfl(wf, b48 + j + 1);
                uint2 vA = *(const uint2*)(xw_a8 + (((unsigned)sA) << 9) + goff);
                uint2 vB = *(const uint2*)(xw_a8 + (((unsigned)sB) << 9) + goff);
                f32x2 mA = {alA, alA}, mB = {alB, alB};
                a0 += __builtin_amdgcn_cvt_pk_f32_fp8((int)vA.x, false) * mA;
                a1 += __builtin_amdgcn_cvt_pk_f32_fp8((int)vA.x, true) * mA;
                a2 += __builtin_amdgcn_cvt_pk_f32_fp8((int)vA.y, false) * mA;
                a3 += __builtin_amdgcn_cvt_pk_f32_fp8((int)vA.y, true) * mA;
                a0 += __builtin_amdgcn_cvt_pk_f32_fp8((int)vB.x, false) * mB;
                a1 += __builtin_amdgcn_cvt_pk_f32_fp8((int)vB.x, true) * mB;
                a2 += __builtin_amdgcn_cvt_pk_f32_fp8((int)vB.y, false) * mB;
                a3 += __builtin_amdgcn_cvt_pk_f32_fp8((int)vB.y, true) * mB;
            }
            if (j < deg) {
                int sA = __builtin_amdgcn_readlane(sv, j);
                float alA = __shfl(wf, b48 + j);
                uint2 vA = *(const uint2*)(xw_a8 + (((unsigned)sA) << 9) + goff);
                f32x2 mA = {alA, alA};
                a0 += __builtin_amdgcn_cvt_pk_f32_fp8((int)vA.x, false) * mA;
                a1 += __builtin_amdgcn_cvt_pk_f32_fp8((int)vA.x, true) * mA;
                a2 += __builtin_amdgcn_cvt_pk_f32_fp8((int)vA.y, false) * mA;
                a3 += __builtin_amdgcn_cvt_pk_f32_fp8((int)vA.y, true) * mA;
            }
            {
                uint2 v = *(const uint2*)(xw_a8 + (((unsigned)d) << 9) + goff);
                f32x2 ms = {selfw, selfw};
                a0 += __builtin_amdgcn_cvt_pk_f32_fp8((int)v.x, false) * ms;
                a1 += __builtin_amdgcn_cvt_pk_f32_fp8((int)v.x, true) * ms;
                a2 += __builtin_amdgcn_cvt_pk_f32_fp8((int)v.y, false) * ms;
                a3 += __builtin_amdgcn_cvt_pk_f32_fp8((int)v.y, true) * ms;
            }
            float av[8] = {a0[0], a0[1], a1[0], a1[1], a2[0], a2[1], a3[0], a3[1]};
            #pragma unroll
            for (int k = 0; k < 8; k++) {
                av[k] += __shfl_xor(av[k], 16);
                av[k] += __shfl_xor(av[k], 32);
            }
            if (g == 0) {
                float4 b0 = *(const float4*)(ba + q * 8);
                float4 b1 = *(const float4*)(ba + q * 8 + 4);
                float bb[8] = {b0.x, b0.y, b0.z, b0.w, b1.x, b1.y, b1.z, b1.w};
                unsigned o[4];
                #pragma unroll
                for (int k = 0; k < 4; k++) {
                    float v0 = fmaxf(av[2 * k] + bb[2 * k], 0.f);
                    float v1 = fmaxf(av[2 * k + 1] + bb[2 * k + 1], 0.f);
                    o[k] = (unsigned)f2b(v0) | ((unsigned)f2b(v1) << 16);
                }
                *(uint4*)(xcomb + (size_t)d * 256 + 128 + q * 8) = make_uint4(o[0], o[1], o[2], o[3]);
            }
            return;
        }
        float4 ad4 = *(const float4*)(a_d + (size_t)d * 4);
        float4 asd = *(const float4*)(a_s + (size_t)d * 4);
        float es0 = lrelu(asd.x + ad4.x), es1 = lrelu(asd.y + ad4.y);
        float es2 = lrelu(asd.z + ad4.z), es3 = lrelu(asd.w + ad4.w);
        if (deg <= 64) {
            int sv = 0;
            float e0 = -1e30f, e1 = -1e30f, e2 = -1e30f, e3 = -1e30f;
            if (lane < deg) {
                sv = csr_g[base + lane];
                float4 s4 = *(const float4*)(a_s + (size_t)sv * 4);
                e0 = lrelu(s4.x + ad4.x); e1 = lrelu(s4.y + ad4.y);
                e2 = lrelu(s4.z + ad4.z); e3 = lrelu(s4.w + ad4.w);
            }
            float m0 = e0, m1 = e1, m2 = e2, m3 = e3;
            #pragma unroll
            for (int off = 1; off < 64; off <<= 1) {
                m0 = fmaxf(m0, __shfl_xor(m0, off));
                m1 = fmaxf(m1, __shfl_xor(m1, off));
                m2 = fmaxf(m2, __shfl_xor(m2, off));
                m3 = fmaxf(m3, __shfl_xor(m3, off));
            }
            m0 = fmaxf(m0, es0); m1 = fmaxf(m1, es1);
            m2 = fmaxf(m2, es2); m3 = fmaxf(m3, es3);
            float w0 = (lane < deg) ? __expf(e0 - m0) : 0.f;
            float w1 = (lane < deg) ? __expf(e1 - m1) : 0.f;
            float w2 = (lane < deg) ? __expf(e2 - m2) : 0.f;
            float w3 = (lane < deg) ? __expf(e3 - m3) : 0.f;
            float d0 = w0, d1 = w1, d2 = w2, d3 = w3;
            #pragma unroll
            for (int off = 1; off < 64; off <<= 1) {
                d0 += __shfl_xor(d0, off); d1 += __shfl_xor(d1, off);
                d2 += __shfl_xor(d2, off); d3 += __shfl_xor(d3, off);
            }
            d0 += __expf(es0 - m0); d1 += __expf(es1 - m1);
            d2 += __expf(es2 - m2); d3 += __expf(es3 - m3);
            float r0 = 0.25f / (d0 + 1e-16f), r1 = 0.25f / (d1 + 1e-16f);
            float r2 = 0.25f / (d2 + 1e-16f), r3 = 0.25f / (d3 + 1e-16f);
            w0 *= r0; w1 *= r1; w2 *= r2; w3 *= r3;
            float wsel = (g == 0) ? w0 : (g == 1) ? w1 : (g == 2) ? w2 : w3;
            float selfw = (g == 0) ? __expf(es0 - m0) * r0 : (g == 1) ? __expf(es1 - m1) * r1
                        : (g == 2) ? __expf(es2 - m2) * r2 : __expf(es3 - m3) * r3;
            unsigned goff = (unsigned)(g * 128 + q * 8);
            f32x2 a0 = {0.f, 0.f}, a1 = {0.f, 0.f}, a2 = {0.f, 0.f}, a3 = {0.f, 0.f};
            for (int j = 0; j < deg; j++) {
                int s = __builtin_amdgcn_readlane(sv, j);
                float al = rdlane_f(wsel, j);
                uint2 v = *(const uint2*)(xw_a8 + (((unsigned)s) << 9) + goff);
                f32x2 mA = {al, al};
                a0 += __builtin_amdgcn_cvt_pk_f32_fp8((int)v.x, false) * mA;
                a1 += __builtin_amdgcn_cvt_pk_f32_fp8((int)v.x, true) * mA;
                a2 += __builtin_amdgcn_cvt_pk_f32_fp8((int)v.y, false) * mA;
                a3 += __builtin_amdgcn_cvt_pk_f32_fp8((int)v.y, true) * mA;
            }
            {
                uint2 v = *(const uint2*)(xw_a8 + (((unsigned)d) << 9) + goff);
                f32x2 ms = {selfw, selfw};
                a0 += __builtin_amdgcn_cvt_pk_f32_fp8((int)v.x, false) * ms;
                a1 += __builtin_amdgcn_cvt_pk_f32_fp8((int)v.x, true) * ms;
                a2 += __builtin_amdgcn_cvt_pk_f32_fp8((int)v.y, false) * ms;
                a3 += __builtin_amdgcn_cvt_pk_f32_fp8((int)v.y, true) * ms;
            }
            float av[8] = {a0[0], a0[1], a1[0], a1[1], a2[0], a2[1], a3[0], a3[1]};
            #pragma unroll
            for (int k = 0; k < 8; k++) {
                av[k] += __shfl_xor(av[k], 16);
                av[k] += __shfl_xor(av[k], 32);
            }
            if (g == 0) {
                float4 b0 = *(const float4*)(ba + q * 8);
                float4 b1 = *(const float4*)(ba + q * 8 + 4);
                float bb[8] = {b0.x, b0.y, b0.z, b0.w, b1.x, b1.y, b1.z, b1.w};
                unsigned o[4];
                #pragma unroll
                for (int k = 0; k < 4; k++) {
                    float v0 = fmaxf(av[2 * k] + bb[2 * k], 0.f);
                    float v1 = fmaxf(av[2 * k + 1] + bb[2 * k + 1], 0.f);
                    o[k] = (unsigned)f2b(v0) | ((unsigned)f2b(v1) << 16);
                }
                *(uint4*)(xcomb + (size_t)d * 256 + 128 + q * 8) = make_uint4(o[0], o[1], o[2], o[3]);
            }
        } else {
            int c2 = lane * 2;
            const unsigned short* xa = (const unsigned short*)xw_a8;
            float m0 = es0, m1 = es1, m2 = es2, m3 = es3;
            for (int i = base; i < end; i += 64) {
                int c = min(64, end - i);
                float t0 = -1e30f, t1 = -1e30f, t2 = -1e30f, t3 = -1e30f;
                if (lane < c) {
                    int s = csr_g[i + lane];
                    float4 s4 = *(const float4*)(a_s + (size_t)s * 4);
                    t0 = lrelu(s4.x + ad4.x); t1 = lrelu(s4.y + ad4.y);
                    t2 = lrelu(s4.z + ad4.z); t3 = lrelu(s4.w + ad4.w);
                }
                m0 = fmaxf(m0, t0); m1 = fmaxf(m1, t1);
                m2 = fmaxf(m2, t2); m3 = fmaxf(m3, t3);
            }
            #pragma unroll
            for (int off = 1; off < 64; off <<= 1) {
                m0 = fmaxf(m0, __shfl_xor(m0, off));
                m1 = fmaxf(m1, __shfl_xor(m1, off));
                m2 = fmaxf(m2, __shfl_xor(m2, off));
                m3 = fmaxf(m3, __shfl_xor(m3, off));
            }
            float d0 = 0.f, d1 = 0.f, d2 = 0.f, d3 = 0.f;
            for (int i = base; i < end; i += 64) {
                int c = min(64, end - i);
                if (lane < c) {
                    int s = csr_g[i + lane];
                    float4 s4 = *(const float4*)(a_s + (size_t)s * 4);
                    d0 += __expf(lrelu(s4.x + ad4.x) - m0);
                    d1 += __expf(lrelu(s4.y + ad4.y) - m1);
                    d2 += __expf(lrelu(s4.z + ad4.z) - m2);
                    d3 += __expf(lrelu(s4.w + ad4.w) - m3);
                }
            }
            #pragma unroll
            for (int off = 1; off < 64; off <<= 1) {
                d0 += __shfl_xor(d0, off); d1 += __shfl_xor(d1, off);
                d2 += __shfl_xor(d2, off); d3 += __shfl_xor(d3, off);
            }
            d0 += __expf(es0 - m0); d1 += __expf(es1 - m1);
            d2 += __expf(es2 - m2); d3 += __expf(es3 - m3);
            float r0 = 1.f / (d0 + 1e-16f), r1 = 1.f / (d1 + 1e-16f);
            float r2 = 1.f / (d2 + 1e-16f), r3 = 1.f / (d3 + 1e-16f);
            float ax = 0.f, ay = 0.f;
            for (int i = base; i < end; i += 64) {
                int c = min(64, end - i);
                int sv = 0;
                float w0 = 0.f, w1 = 0.f, w2 = 0.f, w3 = 0.f;
                if (lane < c) {
                    sv = csr_g[i + lane];
                    float4 s4 = *(const float4*)(a_s + (size_t)sv * 4);
                    w0 = __expf(lrelu(s4.x + ad4.x) - m0) * r0;
                    w1 = __expf(lrelu(s4.y + ad4.y) - m1) * r1;
                    w2 = __expf(lrelu(s4.z + ad4.z) - m2) * r2;
                    w3 = __expf(lrelu(s4.w + ad4.w) - m3) * r3;
                }
                for (int j = 0; j < c; j++) {
                    int s = __shfl(sv, j);
                    float a0 = __shfl(w0, j), a1 = __shfl(w1, j);
                    float a2 = __shfl(w2, j), a3 = __shfl(w3, j);
                    const unsigned short* row = xa + (size_t)s * 256 + lane;
                    f32x2 v0 = fp8x2_to_f32(row[0]);
                    f32x2 v1 = fp8x2_to_f32(row[64]);
                    f32x2 v2 = fp8x2_to_f32(row[128]);
                    f32x2 v3 = fp8x2_to_f32(row[192]);
                    ax = fmaf(v0[0], a0, ax); ay = fmaf(v0[1], a0, ay);
                    ax = fmaf(v1[0], a1, ax); ay = fmaf(v1[1], a1, ay);
                    ax = fmaf(v2[0], a2, ax); ay = fmaf(v2[1], a2, ay);
                    ax = fmaf(v3[0], a3, ax); ay = fmaf(v3[1], a3, ay);
                }
            }
            float s0 = __expf(es0 - m0) * r0, s1 = __expf(es1 - m1) * r1;
            float s2 = __expf(es2 - m2) * r2, s3 = __expf(es3 - m3) * r3;
            const unsigned short* row = xa + (size_t)d * 256 + lane;
            f32x2 v0 = fp8x2_to_f32(row[0]);
            f32x2 v1 = fp8x2_to_f32(row[64]);
            f32x2 v2 = fp8x2_to_f32(row[128]);
            f32x2 v3 = fp8x2_to_f32(row[192]);
            ax = fmaf(v0[0], s0, ax); ay = fmaf(v0[1], s0, ay);
            ax = fmaf(v1[0], s1, ax); ay = fmaf(v1[1], s1, ay);
            ax = fmaf(v2[0], s2, ax); ay = fmaf(v2[1], s2, ay);
            ax = fmaf(v3[0], s3, ax); ay = fmaf(v3[1], s3, ay);
            float ox = fmaxf(0.25f * ax + ba[c2], 0.f);
            float oy = fmaxf(0.25f * ay + ba[c2 + 1], 0.f);
            unsigned uo = (unsigned)f2b(ox) | ((unsigned)f2b(oy) << 16);
            *(unsigned*)(xcomb + (size_t)d * 256 + 128 + c2) = uo;
        }
    }
}

// ---------- D7: pooled GEMM + column-mean; last block computes the heads ----------
__global__ __launch_bounds__(256) void mfma_pool_head(
    const unsigned short* __restrict__ A, const unsigned short* __restrict__ Bt,
    const float* __restrict__ bp, float* __restrict__ sumvec, int* __restrict__ counter,
    int M,
    const float* __restrict__ Wc1, const float* __restrict__ bc1,
    const float* __restrict__ Wc2, const float* __restrict__ bc2,
    const float* __restrict__ Wu, const float* __restrict__ bu,
    float* __restrict__ out)
{
    __shared__ unsigned short As[128 * 128];
    __shared__ unsigned short Bs[128 * 128];
    __shared__ float red[128];
    __shared__ int lastflag;
    int tid = threadIdx.x;
    int lane = tid & 63, w = tid >> 6;
    int wr = w >> 1, wc = w & 1;
    int l16 = lane & 15, lhi = lane >> 4;
    int m0 = blockIdx.x * 128;
    f32x4 acc[4][4] = {};
    for (int kb = 0; kb < 256; kb += 128) {
        if (kb) __syncthreads();
        #pragma unroll
        for (int i = 0; i < 8; i++) {
            int u = tid + i * 256;
            int row = u >> 4, e0 = (u & 15) << 3;
            int sw = e0 ^ ((row & 7) << 3);
            bf16x8 va = {};
            int gr = m0 + row;
            if (gr < M) va = *(const bf16x8*)(A + (size_t)gr * 256 + kb + e0);
            *(bf16x8*)(As + row * 128 + sw) = va;
            bf16x8 vb = *(const bf16x8*)(Bt + (size_t)row * 256 + kb + e0);
            *(bf16x8*)(Bs + row * 128 + sw) = vb;
        }
        __syncthreads();
        #pragma unroll
        for (int kk = 0; kk < 4; kk++) {
            int ke = kk * 32 + lhi * 8;
            bf16x8 af[4], bfr[4];
            #pragma unroll
            for (int m = 0; m < 4; m++) {
                int r = wr * 64 + m * 16 + l16;
                af[m] = *(const bf16x8*)(As + r * 128 + (ke ^ ((r & 7) << 3)));
            }
            #pragma unroll
            for (int n = 0; n < 4; n++) {
                int r = wc * 64 + n * 16 + l16;
                bfr[n] = *(const bf16x8*)(Bs + r * 128 + (ke ^ ((r & 7) << 3)));
            }
            #pragma unroll
            for (int m = 0; m < 4; m++)
                #pragma unroll
                for (int n = 0; n < 4; n++)
                    acc[m][n] = __builtin_amdgcn_mfma_f32_16x16x32_bf16(af[m], bfr[n], acc[m][n], 0, 0, 0);
        }
    }
    float bcol[4];
    #pragma unroll
    for (int n = 0; n < 4; n++) bcol[n] = bp[wc * 64 + n * 16 + l16];
    float colsum[4] = {0.f, 0.f, 0.f, 0.f};
    #pragma unroll
    for (int m = 0; m < 4; m++) {
        #pragma unroll
        for (int r = 0; r < 4; r++) {
            int row_g = m0 + wr * 64 + m * 16 + lhi * 4 + r;
            if (row_g < M) {
                #pragma unroll
                for (int n = 0; n < 4; n++)
                    colsum[n] += fmaxf(acc[m][n][r] + bcol[n], 0.f);
            }
        }
    }
    #pragma unroll
    for (int n = 0; n < 4; n++) {
        colsum[n] += __shfl_xor(colsum[n], 16);
        colsum[n] += __shfl_xor(colsum[n], 32);
    }
    if (tid < 128) red[tid] = 0.f;
    __syncthreads();
    if (lhi == 0) {
        #pragma unroll
        for (int n = 0; n < 4; n++)
            atomicAdd(&red[wc * 64 + n * 16 + l16], colsum[n]);
    }
    __syncthreads();
    if (tid < 128) atomicAdd(&sumvec[tid], red[tid]);
    // ---- last-block heads epilogue ----
    __threadfence();
    __syncthreads();
    if (tid == 0) lastflag = (atomicAdd(counter, 1) == (int)gridDim.x - 1);
    __syncthreads();
    if (!lastflag) return;
    __shared__ float xf[128];
    __shared__ float h1[64];
    if (tid < 128) xf[tid] = atomicAdd(&sumvec[tid], 0.f) * (1.0f / N_NODES);
    __syncthreads();
    if (tid < 64) {
        float s = bc1[tid];
        for (int c = 0; c < 128; c++) s = fmaf(xf[c], Wc1[c * 64 + tid], s);
        h1[tid] = fmaxf(s, 0.f);
    }
    __syncthreads();
    if (tid < 16) {
        float s = bc2[tid];
        for (int j = 0; j < 64; j++) s = fmaf(h1[j], Wc2[j * 16 + tid], s);
        out[tid] = s;
        float u = bu[tid];
        for (int c = 0; c < 128; c++) u = fmaf(xf[c], Wu[c * 16 + tid], u);
        out[16 + tid] = 1.0f / (1.0f + expf(-u));
    }
}

extern "C" void kernel_launch(void* const* d_in, const int* in_sizes, int n_in,
                              void* d_out, int out_size, void* d_ws, size_t ws_size,
                              hipStream_t stream) {
    const float* x    = (const float*)d_in[0];
    const int*   lei  = (const int*)d_in[1];
    const int*   gei  = (const int*)d_in[2];
    const float* W1   = (const float*)d_in[3];
    const float* b1   = (const float*)d_in[4];
    const float* Wg   = (const float*)d_in[5];
    const float* bg   = (const float*)d_in[6];
    const float* Wa   = (const float*)d_in[7];
    const float* atts = (const float*)d_in[8];
    const float* attd = (const float*)d_in[9];
    const float* ba   = (const float*)d_in[10];
    const float* Wp   = (const float*)d_in[11];
    const float* bp   = (const float*)d_in[12];
    const float* Wc1  = (const float*)d_in[13];
    const float* bc1  = (const float*)d_in[14];
    const float* Wc2  = (const float*)d_in[15];
    const float* bc2  = (const float*)d_in[16];
    const float* Wu   = (const float*)d_in[17];
    const float* bu   = (const float*)d_in[18];

    const int* lsrc = lei;
    const int* ldst = lei + EL;
    const int* gsrc = gei;
    const int* gdst = gei + EG;

    uintptr_t base = (uintptr_t)d_ws;
    auto alloc = [&](size_t bytes) { void* p = (void*)base; base += (bytes + 255) & ~(size_t)255; return p; };
    unsigned short* x_loc  = (unsigned short*)alloc((size_t)N_NODES * 128 * 2);
    unsigned char*  xw_g8  = (unsigned char*)alloc((size_t)N_NODES * 128);
    unsigned char*  xw_a8  = (unsigned char*)alloc((size_t)N_NODES * 512);
    unsigned short* xcomb  = (unsigned short*)alloc((size_t)N_NODES * 256 * 2);
    unsigned short* W1t    = (unsigned short*)alloc((size_t)128 * 128 * 2);
    unsigned short* Wgt    = (unsigned short*)alloc((size_t)128 * 128 * 2);
    unsigned short* Wat    = (unsigned short*)alloc((size_t)512 * 128 * 2);
    unsigned short* Wpt    = (unsigned short*)alloc((size_t)128 * 256 * 2);
    float* dinv       = (float*)alloc((size_t)N_NODES * 4);
    float* a_s        = (float*)alloc((size_t)N_NODES * 4 * 4);
    float* a_d        = (float*)alloc((size_t)N_NODES * 4 * 4);
    int*   ghist      = (int*)alloc((size_t)2 * NB * 4);
    int*   bbase      = (int*)alloc((size_t)2 * (NB + 1) * 4);
    int*   gcur       = (int*)alloc((size_t)2 * NB * 4);
    unsigned* ebuf_l  = (unsigned*)alloc((size_t)EL * 4);
    unsigned* ebuf_g  = (unsigned*)alloc((size_t)EG * 4);
    int*   offs_l     = (int*)alloc(((size_t)N_NODES + 1) * 4);
    int*   offs_g     = (int*)alloc(((size_t)N_NODES + 1) * 4);
    unsigned short* csr_l = (unsigned short*)alloc((size_t)EL * 2);
    unsigned short* csr_g = (unsigned short*)alloc((size_t)EG * 2);
    float* sumvec     = (float*)alloc(128 * 4 + 256);
    int*   counter    = (int*)(sumvec + 128);

    hipMemsetAsync(ghist, 0, (size_t)2 * NB * 4, stream);
    hipMemsetAsync(sumvec, 0, 128 * 4 + 4, stream);   // sumvec + counter

    // D1: weights -> bf16^T + bucket histogram
    conv_hist<<<757, 256, 0, stream>>>(W1, W1t, Wg, Wgt, Wa, Wat, Wp, Wpt,
                                       ldst, gdst, ghist);
    // D2: bucket scan (2 blocks) || x_local GEMM (391 blocks)
    scan_gemmx<<<393, 256, 0, stream>>>(ghist, bbase, gcur, x, W1t, b1, x_loc, N_NODES);
    // D3: edge partition (lean)
    bucket_part<<<245, 256, 0, stream>>>(lsrc, ldst, gsrc, gdst, gcur, ebuf_l, ebuf_g);
    // D4: per-bucket CSR + dinv
    bucket_csr<<<392, 256, 0, stream>>>(ebuf_l, ebuf_g, bbase, offs_l, offs_g,
                                        csr_l, csr_g, dinv);
    // D5: Wg + 4 Wa GEMMs, A staged once, xw_g pre-scaled by dinv
    gemm_gw5<<<GB, 256, 0, stream>>>(x_loc, Wgt, Wat, xw_g8, xw_a8, N_NODES,
                                     atts, attd, a_s, a_d, dinv);
    // D6: both gathers
    fused_gather<<<25000, 256, 0, stream>>>(offs_l, csr_l, xw_g8, dinv, bg,
                                            offs_g, csr_g, a_s, a_d, xw_a8, ba, xcomb);
    // D7: pool + heads (last-block epilogue)
    mfma_pool_head<<<GB, 256, 0, stream>>>(xcomb, Wpt, bp, sumvec, counter, N_NODES,
                                           Wc1, bc1, Wc2, bc2, Wu, bu, (float*)d_out);
}

// Round 14
// 171.557 us; speedup vs baseline: 1.2046x; 1.0913x over previous
//
#include <hip/hip_runtime.h>
#include <hip/hip_bf16.h>

#define N_NODES 50000
#define F_IN 128
#define HID 128
#define N_OUT 16
#define HEADS 4
#define EL 800000
#define EG 200000
#define NEG_SLOPE 0.2f
#define NB 196    // buckets of 256 nodes
#define GB 391    // ceil(50000/128)

typedef short bf16x8 __attribute__((ext_vector_type(8)));
typedef float f32x4 __attribute__((ext_vector_type(4)));
typedef float f32x2 __attribute__((ext_vector_type(2)));

static __device__ __forceinline__ float lrelu(float x) {
    return x > 0.f ? x : NEG_SLOPE * x;
}
static __device__ __forceinline__ unsigned short f2b(float f) {
    __hip_bfloat16 h = __float2bfloat16(f);
    return *reinterpret_cast<unsigned short*>(&h);
}
static __device__ __forceinline__ unsigned char f2fp8(float f) {
    unsigned pk = __builtin_amdgcn_cvt_pk_fp8_f32(f, f, 0, false);
    return (unsigned char)(pk & 0xFF);
}
static __device__ __forceinline__ f32x2 fp8x2_to_f32(unsigned u) {
    return __builtin_amdgcn_cvt_pk_f32_fp8((int)u, false);
}
static __device__ __forceinline__ float rdlane_f(float v, int l) {
    return __int_as_float(__builtin_amdgcn_readlane(__float_as_int(v), l));
}

// ---------- D1: weight conversions + bucket histogram ----------
__global__ __launch_bounds__(256) void conv_hist(
    const float* __restrict__ W1, unsigned short* __restrict__ W1t,
    const float* __restrict__ Wg, unsigned short* __restrict__ Wgt,
    const float* __restrict__ Wa, unsigned short* __restrict__ Wat,
    const float* __restrict__ Wp, unsigned short* __restrict__ Wpt,
    const int* __restrict__ ldst, const int* __restrict__ gdst, int* __restrict__ ghist)
{
    int b = blockIdx.x, t = threadIdx.x;
    if (b < 64) {                         // W1 [128][128] -> [n][k]
        int idx = b * 256 + t;
        int k = idx >> 7, n = idx & 127;
        W1t[n * 128 + k] = f2b(W1[idx]);
    } else if (b < 128) {                 // Wg
        int idx = (b - 64) * 256 + t;
        int k = idx >> 7, n = idx & 127;
        Wgt[n * 128 + k] = f2b(Wg[idx]);
    } else if (b < 384) {                 // Wa [128][512] -> [512][128]
        int idx = (b - 128) * 256 + t;
        int k = idx >> 9, n = idx & 511;
        Wat[(size_t)n * 128 + k] = f2b(Wa[idx]);
    } else if (b < 512) {                 // Wp [256][128] -> [128][256]
        int idx = (b - 384) * 256 + t;
        int k = idx >> 7, n = idx & 127;
        Wpt[(size_t)n * 256 + k] = f2b(Wp[idx]);
    } else {                              // bucket histogram
        __shared__ int lh[NB];
        int blk = b - 512;
        bool loc = blk < 196;
        const int* dstp = loc ? ldst : gdst;
        int nE = loc ? EL : EG;
        int* gh = ghist + (loc ? 0 : NB);
        int start = (loc ? blk : blk - 196) * 4096;
        if (t < NB) lh[t] = 0;
        __syncthreads();
        #pragma unroll
        for (int i = 0; i < 16; i++) {
            int e = start + i * 256 + t;
            if (e < nE) atomicAdd(&lh[dstp[e] >> 8], 1);
        }
        __syncthreads();
        if (t < NB && lh[t]) atomicAdd(&gh[t], lh[t]);
    }
}

// ---------- D2: bucket scan (blocks 0-1, block 0 zeroes sumvec) + gemm_x ----------
__global__ __launch_bounds__(256) void scan_gemmx(
    const int* __restrict__ ghist, int* __restrict__ bbase, int* __restrict__ gcur,
    float* __restrict__ sumvec,
    const float* __restrict__ A, const unsigned short* __restrict__ Bt,
    const float* __restrict__ bias, unsigned short* __restrict__ out, int M)
{
    __shared__ unsigned short As[128 * 128];
    __shared__ unsigned short Bs[128 * 128];
    int tid = threadIdx.x;
    if (blockIdx.x < 2) {
        int* s = (int*)As;
        int g = blockIdx.x, t = tid;
        if (g == 0 && t < 128) sumvec[t] = 0.f;
        int v = (t < NB) ? ghist[g * NB + t] : 0;
        s[t] = v;
        __syncthreads();
        for (int off = 1; off < 256; off <<= 1) {
            int u = (t >= off) ? s[t - off] : 0;
            __syncthreads();
            s[t] += u;
            __syncthreads();
        }
        if (t < NB) {
            bbase[g * (NB + 1) + t] = s[t] - v;
            gcur[g * NB + t] = s[t] - v;
        }
        if (t == NB - 1) bbase[g * (NB + 1) + NB] = s[t];
        return;
    }
    int lane = tid & 63, w = tid >> 6;
    int wr = w >> 1, wc = w & 1;
    int l16 = lane & 15, lhi = lane >> 4;
    int m0 = (blockIdx.x - 2) * 128;
    f32x4 acc[4][4] = {};
    #pragma unroll
    for (int i = 0; i < 8; i++) {
        int u = tid + i * 256;
        int row = u >> 4, e0 = (u & 15) << 3;
        int sw = e0 ^ ((row & 7) << 3);
        int gr = m0 + row;
        unsigned short pb[8] = {};
        if (gr < M) {
            float4 a0 = *(const float4*)(A + (size_t)gr * 128 + e0);
            float4 a1 = *(const float4*)(A + (size_t)gr * 128 + e0 + 4);
            pb[0] = f2b(a0.x); pb[1] = f2b(a0.y); pb[2] = f2b(a0.z); pb[3] = f2b(a0.w);
            pb[4] = f2b(a1.x); pb[5] = f2b(a1.y); pb[6] = f2b(a1.z); pb[7] = f2b(a1.w);
        }
        *(bf16x8*)(As + row * 128 + sw) = *(bf16x8*)pb;
        bf16x8 vb = *(const bf16x8*)(Bt + (size_t)row * 128 + e0);
        *(bf16x8*)(Bs + row * 128 + sw) = vb;
    }
    __syncthreads();
    #pragma unroll
    for (int kk = 0; kk < 4; kk++) {
        int ke = kk * 32 + lhi * 8;
        bf16x8 af[4], bfr[4];
        #pragma unroll
        for (int m = 0; m < 4; m++) {
            int r = wr * 64 + m * 16 + l16;
            af[m] = *(const bf16x8*)(As + r * 128 + (ke ^ ((r & 7) << 3)));
        }
        #pragma unroll
        for (int n = 0; n < 4; n++) {
            int r = wc * 64 + n * 16 + l16;
            bfr[n] = *(const bf16x8*)(Bs + r * 128 + (ke ^ ((r & 7) << 3)));
        }
        #pragma unroll
        for (int m = 0; m < 4; m++)
            #pragma unroll
            for (int n = 0; n < 4; n++)
                acc[m][n] = __builtin_amdgcn_mfma_f32_16x16x32_bf16(af[m], bfr[n], acc[m][n], 0, 0, 0);
    }
    #pragma unroll
    for (int m = 0; m < 4; m++) {
        #pragma unroll
        for (int r = 0; r < 4; r++) {
            int row_g = m0 + wr * 64 + m * 16 + lhi * 4 + r;
            if (row_g >= M) continue;
            #pragma unroll
            for (int n = 0; n < 4; n++) {
                int col_g = wc * 64 + n * 16 + l16;
                float v = fmaxf(acc[m][n][r] + bias[col_g], 0.f);
                out[(size_t)row_g * 128 + col_g] = f2b(v);
            }
        }
    }
}

// ---------- D3: edge partition into bucket-contiguous ebuf (lean kernel) ----------
__global__ __launch_bounds__(256) void bucket_part(
    const int* __restrict__ lsrc, const int* __restrict__ ldst,
    const int* __restrict__ gsrc, const int* __restrict__ gdst,
    int* __restrict__ gcur, unsigned* __restrict__ ebuf_l, unsigned* __restrict__ ebuf_g)
{
    __shared__ int lhist[NB], lbase[NB];
    int blk = blockIdx.x, t = threadIdx.x;
    bool loc = blk < 196;
    const int* srcp = loc ? lsrc : gsrc;
    const int* dstp = loc ? ldst : gdst;
    int nE = loc ? EL : EG;
    unsigned* ebuf = loc ? ebuf_l : ebuf_g;
    int* cur = gcur + (loc ? 0 : NB);
    int start = (loc ? blk : blk - 196) * 4096;
    if (t < NB) lhist[t] = 0;
    __syncthreads();
    unsigned pk[16];
    #pragma unroll
    for (int i = 0; i < 16; i++) {
        int e = start + i * 256 + t;
        if (e < nE) {
            unsigned d = (unsigned)dstp[e];
            pk[i] = (d << 16) | (unsigned)srcp[e];
            atomicAdd(&lhist[d >> 8], 1);
        } else pk[i] = 0xFFFFFFFFu;
    }
    __syncthreads();
    if (t < NB) lbase[t] = atomicAdd(&cur[t], lhist[t]);
    __syncthreads();
    if (t < NB) lhist[t] = 0;
    __syncthreads();
    #pragma unroll
    for (int i = 0; i < 16; i++) {
        unsigned b = pk[i] >> 24;
        if (b < NB) {
            int r = atomicAdd(&lhist[b], 1);
            ebuf[lbase[b] + r] = pk[i];
        }
    }
}

// ---------- D4: per-bucket fine CSR + dinv ----------
__global__ __launch_bounds__(256) void bucket_csr(
    const unsigned* __restrict__ ebuf_l, const unsigned* __restrict__ ebuf_g,
    const int* __restrict__ bbase,
    int* __restrict__ offs_l, int* __restrict__ offs_g,
    unsigned short* __restrict__ csr_l, unsigned short* __restrict__ csr_g,
    float* __restrict__ dinv)
{
    __shared__ int cnt[256], s[256], cur[256];
    int blk = blockIdx.x, t = threadIdx.x;
    bool loc = blk < 196;
    int b = loc ? blk : blk - 196;
    const unsigned* ebuf = loc ? ebuf_l : ebuf_g;
    const int* bb = bbase + (loc ? 0 : NB + 1);
    int* offs = loc ? offs_l : offs_g;
    unsigned short* csr = loc ? csr_l : csr_g;
    int rs = bb[b], re = bb[b + 1];
    cnt[t] = 0;
    __syncthreads();
    for (int i = rs + t; i < re; i += 256) atomicAdd(&cnt[(ebuf[i] >> 16) & 255], 1);
    __syncthreads();
    int v = cnt[t];
    s[t] = v;
    __syncthreads();
    for (int off = 1; off < 256; off <<= 1) {
        int u = (t >= off) ? s[t - off] : 0;
        __syncthreads();
        s[t] += u;
        __syncthreads();
    }
    int excl = s[t] - v;
    int node = b * 256 + t;
    cur[t] = rs + excl;
    if (node < N_NODES) {
        offs[node] = rs + excl;
        if (loc) dinv[node] = rsqrtf((float)(v + 1));
    }
    if (blk == 0 && t == 0) offs_l[N_NODES] = EL;
    if (blk == 196 && t == 0) offs_g[N_NODES] = EG;
    __syncthreads();
    for (int i = rs + t; i < re; i += 256) {
        unsigned pk = ebuf[i];
        int r = atomicAdd(&cur[(pk >> 16) & 255], 1);
        csr[r] = (unsigned short)(pk & 0xFFFFu);
    }
}

// ---------- D5: Wg + 4×Wa GEMMs, A staged once; xw_g pre-scaled by dinv ----------
__global__ __launch_bounds__(256) void gemm_gw5(
    const unsigned short* __restrict__ A, const unsigned short* __restrict__ Wgt,
    const unsigned short* __restrict__ Wat,
    unsigned char* __restrict__ xw_g8, unsigned char* __restrict__ xw_a8, int M,
    const float* __restrict__ atts, const float* __restrict__ attd,
    float* __restrict__ a_s, float* __restrict__ a_d,
    const float* __restrict__ dinv)
{
    __shared__ unsigned short As[128 * 128];
    __shared__ unsigned short Bs[128 * 128];
    __shared__ float sas[128], sad[128];
    int tid = threadIdx.x;
    int lane = tid & 63, w = tid >> 6;
    int wr = w >> 1, wc = w & 1;
    int l16 = lane & 15, lhi = lane >> 4;
    int m0 = blockIdx.x * 128;
    #pragma unroll
    for (int i = 0; i < 8; i++) {
        int u = tid + i * 256;
        int row = u >> 4, e0 = (u & 15) << 3;
        int sw = e0 ^ ((row & 7) << 3);
        bf16x8 va = {};
        int gr = m0 + row;
        if (gr < M) va = *(const bf16x8*)(A + (size_t)gr * 128 + e0);
        *(bf16x8*)(As + row * 128 + sw) = va;
    }
    for (int p = 0; p < 5; p++) {
        const unsigned short* Bt = (p == 0) ? Wgt : (Wat + (size_t)(p - 1) * 128 * 128);
        __syncthreads();
        #pragma unroll
        for (int i = 0; i < 8; i++) {
            int u = tid + i * 256;
            int row = u >> 4, e0 = (u & 15) << 3;
            int sw = e0 ^ ((row & 7) << 3);
            bf16x8 vb = *(const bf16x8*)(Bt + (size_t)row * 128 + e0);
            *(bf16x8*)(Bs + row * 128 + sw) = vb;
        }
        if (tid < 128) { sas[tid] = 0.f; sad[tid] = 0.f; }
        __syncthreads();
        f32x4 acc[4][4] = {};
        #pragma unroll
        for (int kk = 0; kk < 4; kk++) {
            int ke = kk * 32 + lhi * 8;
            bf16x8 af[4], bfr[4];
            #pragma unroll
            for (int m = 0; m < 4; m++) {
                int r = wr * 64 + m * 16 + l16;
                af[m] = *(const bf16x8*)(As + r * 128 + (ke ^ ((r & 7) << 3)));
            }
            #pragma unroll
            for (int n = 0; n < 4; n++) {
                int r = wc * 64 + n * 16 + l16;
                bfr[n] = *(const bf16x8*)(Bs + r * 128 + (ke ^ ((r & 7) << 3)));
            }
            #pragma unroll
            for (int m = 0; m < 4; m++)
                #pragma unroll
                for (int n = 0; n < 4; n++)
                    acc[m][n] = __builtin_amdgcn_mfma_f32_16x16x32_bf16(af[m], bfr[n], acc[m][n], 0, 0, 0);
        }
        if (p == 0) {
            #pragma unroll
            for (int m = 0; m < 4; m++)
                #pragma unroll
                for (int r = 0; r < 4; r++) {
                    int row_g = m0 + wr * 64 + m * 16 + lhi * 4 + r;
                    if (row_g >= M) continue;
                    float dv = dinv[row_g];
                    #pragma unroll
                    for (int n = 0; n < 4; n++) {
                        int col_g = wc * 64 + n * 16 + l16;
                        xw_g8[(size_t)row_g * 128 + col_g] = f2fp8(acc[m][n][r] * dv);
                    }
                }
        } else {
            int head = p - 1;
            float ats[4], atd[4];
            #pragma unroll
            for (int n = 0; n < 4; n++) {
                int cl = wc * 64 + n * 16 + l16;
                ats[n] = atts[head * 128 + cl];
                atd[n] = attd[head * 128 + cl];
            }
            #pragma unroll
            for (int m = 0; m < 4; m++) {
                #pragma unroll
                for (int r = 0; r < 4; r++) {
                    int row_l = wr * 64 + m * 16 + lhi * 4 + r;
                    int row_g = m0 + row_l;
                    float ps = 0.f, pd = 0.f;
                    #pragma unroll
                    for (int n = 0; n < 4; n++) {
                        float v = acc[m][n][r];
                        ps = fmaf(v, ats[n], ps);
                        pd = fmaf(v, atd[n], pd);
                        if (row_g < M) {
                            int col_g = head * 128 + wc * 64 + n * 16 + l16;
                            xw_a8[(size_t)row_g * 512 + col_g] = f2fp8(v);
                        }
                    }
                    #pragma unroll
                    for (int off = 1; off < 16; off <<= 1) {
                        ps += __shfl_xor(ps, off);
                        pd += __shfl_xor(pd, off);
                    }
                    if (l16 == 0) {
                        atomicAdd(&sas[row_l], ps);
                        atomicAdd(&sad[row_l], pd);
                    }
                }
            }
            __syncthreads();
            if (tid < 128) {
                int row_g = m0 + tid;
                if (row_g < M) {
                    a_s[(size_t)row_g * 4 + head] = sas[tid];
                    a_d[(size_t)row_g * 4 + head] = sad[tid];
                }
            }
        }
    }
}

// ---------- D6: fused gathers (GCN maskless full-steps) ----------
__global__ __launch_bounds__(256) void fused_gather(
    const int* __restrict__ offs_l, const unsigned short* __restrict__ csr_l,
    const unsigned char* __restrict__ xw_g8, const float* __restrict__ dinv,
    const float* __restrict__ bg,
    const int* __restrict__ offs_g, const unsigned short* __restrict__ csr_g,
    const float* __restrict__ a_s, const float* __restrict__ a_d,
    const unsigned char* __restrict__ xw_a8, const float* __restrict__ ba,
    unsigned short* __restrict__ xcomb)
{
    int blk = blockIdx.x;
    int tid = threadIdx.x;
    int lane = tid & 63;
    int g = lane >> 4, q = lane & 15;
    if (blk < 12500) {
        int d = (blk * 256 + tid) >> 6;
        if (d >= N_NODES) return;
        int base = offs_l[d], end = offs_l[d + 1];
        unsigned goff = (unsigned)q * 8u;
        f32x2 a0 = {0.f, 0.f}, a1 = {0.f, 0.f}, a2 = {0.f, 0.f}, a3 = {0.f, 0.f};
        for (int i = base; i < end; ) {
            int chunk = min(64, end - i);
            int sv = (lane < chunk) ? (int)csr_l[i + lane] : 0;
            int nfull = chunk >> 2;          // full steps: 4 in-bounds edges each
            int j = 0;
            for (; j + 2 <= nfull; j += 2) { // 8 edges, maskless
                int eA = j * 4 + g, eB = eA + 4;
                int sA = __shfl(sv, eA);
                int sB = __shfl(sv, eB);
                uint2 vA = *(const uint2*)(xw_g8 + (((unsigned)sA) << 7) + goff);
                uint2 vB = *(const uint2*)(xw_g8 + (((unsigned)sB) << 7) + goff);
                a0 += __builtin_amdgcn_cvt_pk_f32_fp8((int)vA.x, false);
                a1 += __builtin_amdgcn_cvt_pk_f32_fp8((int)vA.x, true);
                a2 += __builtin_amdgcn_cvt_pk_f32_fp8((int)vA.y, false);
                a3 += __builtin_amdgcn_cvt_pk_f32_fp8((int)vA.y, true);
                a0 += __builtin_amdgcn_cvt_pk_f32_fp8((int)vB.x, false);
                a1 += __builtin_amdgcn_cvt_pk_f32_fp8((int)vB.x, true);
                a2 += __builtin_amdgcn_cvt_pk_f32_fp8((int)vB.y, false);
                a3 += __builtin_amdgcn_cvt_pk_f32_fp8((int)vB.y, true);
            }
            for (; j < nfull; j++) {         // maskless single step
                int e = j * 4 + g;
                int s = __shfl(sv, e);
                uint2 v = *(const uint2*)(xw_g8 + (((unsigned)s) << 7) + goff);
                a0 += __builtin_amdgcn_cvt_pk_f32_fp8((int)v.x, false);
                a1 += __builtin_amdgcn_cvt_pk_f32_fp8((int)v.x, true);
                a2 += __builtin_amdgcn_cvt_pk_f32_fp8((int)v.y, false);
                a3 += __builtin_amdgcn_cvt_pk_f32_fp8((int)v.y, true);
            }
            if ((nfull << 2) < chunk) {      // masked tail (0-3 edges)
                int e = (nfull << 2) + g;
                int s = __shfl(sv, e);
                float mk = (e < chunk) ? 1.f : 0.f;
                f32x2 m2 = {mk, mk};
                uint2 v = *(const uint2*)(xw_g8 + (((unsigned)s) << 7) + goff);
                a0 += __builtin_amdgcn_cvt_pk_f32_fp8((int)v.x, false) * m2;
                a1 += __builtin_amdgcn_cvt_pk_f32_fp8((int)v.x, true) * m2;
                a2 += __builtin_amdgcn_cvt_pk_f32_fp8((int)v.y, false) * m2;
                a3 += __builtin_amdgcn_cvt_pk_f32_fp8((int)v.y, true) * m2;
            }
            i += chunk;
        }
        float av[8] = {a0[0], a0[1], a1[0], a1[1], a2[0], a2[1], a3[0], a3[1]};
        #pragma unroll
        for (int k = 0; k < 8; k++) {
            av[k] += __shfl_xor(av[k], 16);
            av[k] += __shfl_xor(av[k], 32);
        }
        if (g == 0) {
            float dd = dinv[d];
            uint2 sv2 = *(const uint2*)(xw_g8 + (((unsigned)d) << 7) + goff);
            f32x2 s0 = fp8x2_to_f32(sv2.x & 0xFFFFu);
            f32x2 s1 = __builtin_amdgcn_cvt_pk_f32_fp8((int)sv2.x, true);
            f32x2 s2 = fp8x2_to_f32(sv2.y & 0xFFFFu);
            f32x2 s3 = __builtin_amdgcn_cvt_pk_f32_fp8((int)sv2.y, true);
            float sf[8] = {s0[0], s0[1], s1[0], s1[1], s2[0], s2[1], s3[0], s3[1]};
            float4 b0 = *(const float4*)(bg + q * 8);
            float4 b1 = *(const float4*)(bg + q * 8 + 4);
            float bb[8] = {b0.x, b0.y, b0.z, b0.w, b1.x, b1.y, b1.z, b1.w};
            unsigned o[4];
            #pragma unroll
            for (int k = 0; k < 4; k++) {
                float v0 = fmaxf(dd * (av[2 * k] + sf[2 * k]) + bb[2 * k], 0.f);
                float v1 = fmaxf(dd * (av[2 * k + 1] + sf[2 * k + 1]) + bb[2 * k + 1], 0.f);
                o[k] = (unsigned)f2b(v0) | ((unsigned)f2b(v1) << 16);
            }
            *(uint4*)(xcomb + (size_t)d * 256 + q * 8) = make_uint4(o[0], o[1], o[2], o[3]);
        }
    } else {
        int d = ((blk - 12500) * 256 + tid) >> 6;
        if (d >= N_NODES) return;
        int base = offs_g[d], end = offs_g[d + 1];
        int deg = end - base;
        if (deg <= 16) {
            float ad_g = a_d[(size_t)d * 4 + g];
            float es = lrelu(a_s[(size_t)d * 4 + g] + ad_g);
            int sv = (q < deg) ? (int)csr_g[base + q] : 0;
            float asg = a_s[(size_t)sv * 4 + g];
            float e = (q < deg) ? lrelu(asg + ad_g) : -1e30f;
            float m = e;
            m = fmaxf(m, __shfl_xor(m, 1));
            m = fmaxf(m, __shfl_xor(m, 2));
            m = fmaxf(m, __shfl_xor(m, 4));
            m = fmaxf(m, __shfl_xor(m, 8));
            m = fmaxf(m, es);
            float wgt = (q < deg) ? __expf(e - m) : 0.f;
            float den = wgt;
            den += __shfl_xor(den, 1);
            den += __shfl_xor(den, 2);
            den += __shfl_xor(den, 4);
            den += __shfl_xor(den, 8);
            float se = __expf(es - m);
            den += se;
            float rinv = 0.25f / (den + 1e-16f);
            float wf = wgt * rinv;
            float selfw = se * rinv;
            unsigned goff = (unsigned)(g * 128 + q * 8);
            int b48 = lane & 48;
            f32x2 a0 = {0.f, 0.f}, a1 = {0.f, 0.f}, a2 = {0.f, 0.f}, a3 = {0.f, 0.f};
            int j = 0;
            for (; j + 2 <= deg; j += 2) {
                int sA = __builtin_amdgcn_readlane(sv, j);
                int sB = __builtin_amdgcn_readlane(sv, j + 1);
                float alA = __shfl(wf, b48 + j);
                float alB = __shfl(wf, b48 + j + 1);
                uint2 vA = *(const uint2*)(xw_a8 + (((unsigned)sA) << 9) + goff);
                uint2 vB = *(const uint2*)(xw_a8 + (((unsigned)sB) << 9) + goff);
                f32x2 mA = {alA, alA}, mB = {alB, alB};
                a0 += __builtin_amdgcn_cvt_pk_f32_fp8((int)vA.x, false) * mA;
                a1 += __builtin_amdgcn_cvt_pk_f32_fp8((int)vA.x, true) * mA;
                a2 += __builtin_amdgcn_cvt_pk_f32_fp8((int)vA.y, false) * mA;
                a3 += __builtin_amdgcn_cvt_pk_f32_fp8((int)vA.y, true) * mA;
                a0 += __builtin_amdgcn_cvt_pk_f32_fp8((int)vB.x, false) * mB;
                a1 += __builtin_amdgcn_cvt_pk_f32_fp8((int)vB.x, true) * mB;
                a2 += __builtin_amdgcn_cvt_pk_f32_fp8((int)vB.y, false) * mB;
                a3 += __builtin_amdgcn_cvt_pk_f32_fp8((int)vB.y, true) * mB;
            }
            if (j < deg) {
                int sA = __builtin_amdgcn_readlane(sv, j);
                float alA = __shfl(wf, b48 + j);
                uint2 vA = *(const uint2*)(xw_a8 + (((unsigned)sA) << 9) + goff);
                f32x2 mA = {alA, alA};
                a0 += __builtin_amdgcn_cvt_pk_f32_fp8((int)vA.x, false) * mA;
                a1 += __builtin_amdgcn_cvt_pk_f32_fp8((int)vA.x, true) * mA;
                a2 += __builtin_amdgcn_cvt_pk_f32_fp8((int)vA.y, false) * mA;
                a3 += __builtin_amdgcn_cvt_pk_f32_fp8((int)vA.y, true) * mA;
            }
            {
                uint2 v = *(const uint2*)(xw_a8 + (((unsigned)d) << 9) + goff);
                f32x2 ms = {selfw, selfw};
                a0 += __builtin_amdgcn_cvt_pk_f32_fp8((int)v.x, false) * ms;
                a1 += __builtin_amdgcn_cvt_pk_f32_fp8((int)v.x, true) * ms;
                a2 += __builtin_amdgcn_cvt_pk_f32_fp8((int)v.y, false) * ms;
                a3 += __builtin_amdgcn_cvt_pk_f32_fp8((int)v.y, true) * ms;
            }
            float av[8] = {a0[0], a0[1], a1[0], a1[1], a2[0], a2[1], a3[0], a3[1]};
            #pragma unroll
            for (int k = 0; k < 8; k++) {
                av[k] += __shfl_xor(av[k], 16);
                av[k] += __shfl_xor(av[k], 32);
            }
            if (g == 0) {
                float4 b0 = *(const float4*)(ba + q * 8);
                float4 b1 = *(const float4*)(ba + q * 8 + 4);
                float bb[8] = {b0.x, b0.y, b0.z, b0.w, b1.x, b1.y, b1.z, b1.w};
                unsigned o[4];
                #pragma unroll
                for (int k = 0; k < 4; k++) {
                    float v0 = fmaxf(av[2 * k] + bb[2 * k], 0.f);
                    float v1 = fmaxf(av[2 * k + 1] + bb[2 * k + 1], 0.f);
                    o[k] = (unsigned)f2b(v0) | ((unsigned)f2b(v1) << 16);
                }
                *(uint4*)(xcomb + (size_t)d * 256 + 128 + q * 8) = make_uint4(o[0], o[1], o[2], o[3]);
            }
            return;
        }
        float4 ad4 = *(const float4*)(a_d + (size_t)d * 4);
        float4 asd = *(const float4*)(a_s + (size_t)d * 4);
        float es0 = lrelu(asd.x + ad4.x), es1 = lrelu(asd.y + ad4.y);
        float es2 = lrelu(asd.z + ad4.z), es3 = lrelu(asd.w + ad4.w);
        if (deg <= 64) {
            int sv = 0;
            float e0 = -1e30f, e1 = -1e30f, e2 = -1e30f, e3 = -1e30f;
            if (lane < deg) {
                sv = csr_g[base + lane];
                float4 s4 = *(const float4*)(a_s + (size_t)sv * 4);
                e0 = lrelu(s4.x + ad4.x); e1 = lrelu(s4.y + ad4.y);
                e2 = lrelu(s4.z + ad4.z); e3 = lrelu(s4.w + ad4.w);
            }
            float m0 = e0, m1 = e1, m2 = e2, m3 = e3;
            #pragma unroll
            for (int off = 1; off < 64; off <<= 1) {
                m0 = fmaxf(m0, __shfl_xor(m0, off));
                m1 = fmaxf(m1, __shfl_xor(m1, off));
                m2 = fmaxf(m2, __shfl_xor(m2, off));
                m3 = fmaxf(m3, __shfl_xor(m3, off));
            }
            m0 = fmaxf(m0, es0); m1 = fmaxf(m1, es1);
            m2 = fmaxf(m2, es2); m3 = fmaxf(m3, es3);
            float w0 = (lane < deg) ? __expf(e0 - m0) : 0.f;
            float w1 = (lane < deg) ? __expf(e1 - m1) : 0.f;
            float w2 = (lane < deg) ? __expf(e2 - m2) : 0.f;
            float w3 = (lane < deg) ? __expf(e3 - m3) : 0.f;
            float d0 = w0, d1 = w1, d2 = w2, d3 = w3;
            #pragma unroll
            for (int off = 1; off < 64; off <<= 1) {
                d0 += __shfl_xor(d0, off); d1 += __shfl_xor(d1, off);
                d2 += __shfl_xor(d2, off); d3 += __shfl_xor(d3, off);
            }
            d0 += __expf(es0 - m0); d1 += __expf(es1 - m1);
            d2 += __expf(es2 - m2); d3 += __expf(es3 - m3);
            float r0 = 0.25f / (d0 + 1e-16f), r1 = 0.25f / (d1 + 1e-16f);
            float r2 = 0.25f / (d2 + 1e-16f), r3 = 0.25f / (d3 + 1e-16f);
            w0 *= r0; w1 *= r1; w2 *= r2; w3 *= r3;
            float wsel = (g == 0) ? w0 : (g == 1) ? w1 : (g == 2) ? w2 : w3;
            float selfw = (g == 0) ? __expf(es0 - m0) * r0 : (g == 1) ? __expf(es1 - m1) * r1
                        : (g == 2) ? __expf(es2 - m2) * r2 : __expf(es3 - m3) * r3;
            unsigned goff = (unsigned)(g * 128 + q * 8);
            f32x2 a0 = {0.f, 0.f}, a1 = {0.f, 0.f}, a2 = {0.f, 0.f}, a3 = {0.f, 0.f};
            for (int j = 0; j < deg; j++) {
                int s = __builtin_amdgcn_readlane(sv, j);
                float al = rdlane_f(wsel, j);
                uint2 v = *(const uint2*)(xw_a8 + (((unsigned)s) << 9) + goff);
                f32x2 mA = {al, al};
                a0 += __builtin_amdgcn_cvt_pk_f32_fp8((int)v.x, false) * mA;
                a1 += __builtin_amdgcn_cvt_pk_f32_fp8((int)v.x, true) * mA;
                a2 += __builtin_amdgcn_cvt_pk_f32_fp8((int)v.y, false) * mA;
                a3 += __builtin_amdgcn_cvt_pk_f32_fp8((int)v.y, true) * mA;
            }
            {
                uint2 v = *(const uint2*)(xw_a8 + (((unsigned)d) << 9) + goff);
                f32x2 ms = {selfw, selfw};
                a0 += __builtin_amdgcn_cvt_pk_f32_fp8((int)v.x, false) * ms;
                a1 += __builtin_amdgcn_cvt_pk_f32_fp8((int)v.x, true) * ms;
                a2 += __builtin_amdgcn_cvt_pk_f32_fp8((int)v.y, false) * ms;
                a3 += __builtin_amdgcn_cvt_pk_f32_fp8((int)v.y, true) * ms;
            }
            float av[8] = {a0[0], a0[1], a1[0], a1[1], a2[0], a2[1], a3[0], a3[1]};
            #pragma unroll
            for (int k = 0; k < 8; k++) {
                av[k] += __shfl_xor(av[k], 16);
                av[k] += __shfl_xor(av[k], 32);
            }
            if (g == 0) {
                float4 b0 = *(const float4*)(ba + q * 8);
                float4 b1 = *(const float4*)(ba + q * 8 + 4);
                float bb[8] = {b0.x, b0.y, b0.z, b0.w, b1.x, b1.y, b1.z, b1.w};
                unsigned o[4];
                #pragma unroll
                for (int k = 0; k < 4; k++) {
                    float v0 = fmaxf(av[2 * k] + bb[2 * k], 0.f);
                    float v1 = fmaxf(av[2 * k + 1] + bb[2 * k + 1], 0.f);
                    o[k] = (unsigned)f2b(v0) | ((unsigned)f2b(v1) << 16);
                }
                *(uint4*)(xcomb + (size_t)d * 256 + 128 + q * 8) = make_uint4(o[0], o[1], o[2], o[3]);
            }
        } else {
            int c2 = lane * 2;
            const unsigned short* xa = (const unsigned short*)xw_a8;
            float m0 = es0, m1 = es1, m2 = es2, m3 = es3;
            for (int i = base; i < end; i += 64) {
                int c = min(64, end - i);
                float t0 = -1e30f, t1 = -1e30f, t2 = -1e30f, t3 = -1e30f;
                if (lane < c) {
                    int s = csr_g[i + lane];
                    float4 s4 = *(const float4*)(a_s + (size_t)s * 4);
                    t0 = lrelu(s4.x + ad4.x); t1 = lrelu(s4.y + ad4.y);
                    t2 = lrelu(s4.z + ad4.z); t3 = lrelu(s4.w + ad4.w);
                }
                m0 = fmaxf(m0, t0); m1 = fmaxf(m1, t1);
                m2 = fmaxf(m2, t2); m3 = fmaxf(m3, t3);
            }
            #pragma unroll
            for (int off = 1; off < 64; off <<= 1) {
                m0 = fmaxf(m0, __shfl_xor(m0, off));
                m1 = fmaxf(m1, __shfl_xor(m1, off));
                m2 = fmaxf(m2, __shfl_xor(m2, off));
                m3 = fmaxf(m3, __shfl_xor(m3, off));
            }
            float d0 = 0.f, d1 = 0.f, d2 = 0.f, d3 = 0.f;
            for (int i = base; i < end; i += 64) {
                int c = min(64, end - i);
                if (lane < c) {
                    int s = csr_g[i + lane];
                    float4 s4 = *(const float4*)(a_s + (size_t)s * 4);
                    d0 += __expf(lrelu(s4.x + ad4.x) - m0);
                    d1 += __expf(lrelu(s4.y + ad4.y) - m1);
                    d2 += __expf(lrelu(s4.z + ad4.z) - m2);
                    d3 += __expf(lrelu(s4.w + ad4.w) - m3);
                }
            }
            #pragma unroll
            for (int off = 1; off < 64; off <<= 1) {
                d0 += __shfl_xor(d0, off); d1 += __shfl_xor(d1, off);
                d2 += __shfl_xor(d2, off); d3 += __shfl_xor(d3, off);
            }
            d0 += __expf(es0 - m0); d1 += __expf(es1 - m1);
            d2 += __expf(es2 - m2); d3 += __expf(es3 - m3);
            float r0 = 1.f / (d0 + 1e-16f), r1 = 1.f / (d1 + 1e-16f);
            float r2 = 1.f / (d2 + 1e-16f), r3 = 1.f / (d3 + 1e-16f);
            float ax = 0.f, ay = 0.f;
            for (int i = base; i < end; i += 64) {
                int c = min(64, end - i);
                int sv = 0;
                float w0 = 0.f, w1 = 0.f, w2 = 0.f, w3 = 0.f;
                if (lane < c) {
                    sv = csr_g[i + lane];
                    float4 s4 = *(const float4*)(a_s + (size_t)sv * 4);
                    w0 = __expf(lrelu(s4.x + ad4.x) - m0) * r0;
                    w1 = __expf(lrelu(s4.y + ad4.y) - m1) * r1;
                    w2 = __expf(lrelu(s4.z + ad4.z) - m2) * r2;
                    w3 = __expf(lrelu(s4.w + ad4.w) - m3) * r3;
                }
                for (int j = 0; j < c; j++) {
                    int s = __shfl(sv, j);
                    float a0 = __shfl(w0, j), a1 = __shfl(w1, j);
                    float a2 = __shfl(w2, j), a3 = __shfl(w3, j);
                    const unsigned short* row = xa + (size_t)s * 256 + lane;
                    f32x2 v0 = fp8x2_to_f32(row[0]);
                    f32x2 v1 = fp8x2_to_f32(row[64]);
                    f32x2 v2 = fp8x2_to_f32(row[128]);
                    f32x2 v3 = fp8x2_to_f32(row[192]);
                    ax = fmaf(v0[0], a0, ax); ay = fmaf(v0[1], a0, ay);
                    ax = fmaf(v1[0], a1, ax); ay = fmaf(v1[1], a1, ay);
                    ax = fmaf(v2[0], a2, ax); ay = fmaf(v2[1], a2, ay);
                    ax = fmaf(v3[0], a3, ax); ay = fmaf(v3[1], a3, ay);
                }
            }
            float s0 = __expf(es0 - m0) * r0, s1 = __expf(es1 - m1) * r1;
            float s2 = __expf(es2 - m2) * r2, s3 = __expf(es3 - m3) * r3;
            const unsigned short* row = xa + (size_t)d * 256 + lane;
            f32x2 v0 = fp8x2_to_f32(row[0]);
            f32x2 v1 = fp8x2_to_f32(row[64]);
            f32x2 v2 = fp8x2_to_f32(row[128]);
            f32x2 v3 = fp8x2_to_f32(row[192]);
            ax = fmaf(v0[0], s0, ax); ay = fmaf(v0[1], s0, ay);
            ax = fmaf(v1[0], s1, ax); ay = fmaf(v1[1], s1, ay);
            ax = fmaf(v2[0], s2, ax); ay = fmaf(v2[1], s2, ay);
            ax = fmaf(v3[0], s3, ax); ay = fmaf(v3[1], s3, ay);
            float ox = fmaxf(0.25f * ax + ba[c2], 0.f);
            float oy = fmaxf(0.25f * ay + ba[c2 + 1], 0.f);
            unsigned uo = (unsigned)f2b(ox) | ((unsigned)f2b(oy) << 16);
            *(unsigned*)(xcomb + (size_t)d * 256 + 128 + c2) = uo;
        }
    }
}

// ---------- D7: pooled GEMM + column-mean accumulation ----------
__global__ __launch_bounds__(256) void mfma_pool(
    const unsigned short* __restrict__ A, const unsigned short* __restrict__ Bt,
    const float* __restrict__ bp, float* __restrict__ sumvec, int M)
{
    __shared__ unsigned short As[128 * 128];
    __shared__ unsigned short Bs[128 * 128];
    __shared__ float red[128];
    int tid = threadIdx.x;
    int lane = tid & 63, w = tid >> 6;
    int wr = w >> 1, wc = w & 1;
    int l16 = lane & 15, lhi = lane >> 4;
    int m0 = blockIdx.x * 128;
    f32x4 acc[4][4] = {};
    for (int kb = 0; kb < 256; kb += 128) {
        if (kb) __syncthreads();
        #pragma unroll
        for (int i = 0; i < 8; i++) {
            int u = tid + i * 256;
            int row = u >> 4, e0 = (u & 15) << 3;
            int sw = e0 ^ ((row & 7) << 3);
            bf16x8 va = {};
            int gr = m0 + row;
            if (gr < M) va = *(const bf16x8*)(A + (size_t)gr * 256 + kb + e0);
            *(bf16x8*)(As + row * 128 + sw) = va;
            bf16x8 vb = *(const bf16x8*)(Bt + (size_t)row * 256 + kb + e0);
            *(bf16x8*)(Bs + row * 128 + sw) = vb;
        }
        __syncthreads();
        #pragma unroll
        for (int kk = 0; kk < 4; kk++) {
            int ke = kk * 32 + lhi * 8;
            bf16x8 af[4], bfr[4];
            #pragma unroll
            for (int m = 0; m < 4; m++) {
                int r = wr * 64 + m * 16 + l16;
                af[m] = *(const bf16x8*)(As + r * 128 + (ke ^ ((r & 7) << 3)));
            }
            #pragma unroll
            for (int n = 0; n < 4; n++) {
                int r = wc * 64 + n * 16 + l16;
                bfr[n] = *(const bf16x8*)(Bs + r * 128 + (ke ^ ((r & 7) << 3)));
            }
            #pragma unroll
            for (int m = 0; m < 4; m++)
                #pragma unroll
                for (int n = 0; n < 4; n++)
                    acc[m][n] = __builtin_amdgcn_mfma_f32_16x16x32_bf16(af[m], bfr[n], acc[m][n], 0, 0, 0);
        }
    }
    float bcol[4];
    #pragma unroll
    for (int n = 0; n < 4; n++) bcol[n] = bp[wc * 64 + n * 16 + l16];
    float colsum[4] = {0.f, 0.f, 0.f, 0.f};
    #pragma unroll
    for (int m = 0; m < 4; m++) {
        #pragma unroll
        for (int r = 0; r < 4; r++) {
            int row_g = m0 + wr * 64 + m * 16 + lhi * 4 + r;
            if (row_g < M) {
                #pragma unroll
                for (int n = 0; n < 4; n++)
                    colsum[n] += fmaxf(acc[m][n][r] + bcol[n], 0.f);
            }
        }
    }
    #pragma unroll
    for (int n = 0; n < 4; n++) {
        colsum[n] += __shfl_xor(colsum[n], 16);
        colsum[n] += __shfl_xor(colsum[n], 32);
    }
    if (tid < 128) red[tid] = 0.f;
    __syncthreads();
    if (lhi == 0) {
        #pragma unroll
        for (int n = 0; n < 4; n++)
            atomicAdd(&red[wc * 64 + n * 16 + l16], colsum[n]);
    }
    __syncthreads();
    if (tid < 128) atomicAdd(&sumvec[tid], red[tid]);
}

// ---------- D8: final heads (f32 output) ----------
__global__ void final_head(const float* __restrict__ sumvec,
                           const float* __restrict__ Wc1, const float* __restrict__ bc1,
                           const float* __restrict__ Wc2, const float* __restrict__ bc2,
                           const float* __restrict__ Wu, const float* __restrict__ bu,
                           float* __restrict__ out)
{
    __shared__ float xf[128];
    __shared__ float h1[64];
    int t = threadIdx.x;   // 128 threads
    xf[t] = sumvec[t] * (1.0f / N_NODES);
    __syncthreads();
    if (t < 64) {
        float s = bc1[t];
        for (int c = 0; c < 128; c++) s = fmaf(xf[c], Wc1[c * 64 + t], s);
        h1[t] = fmaxf(s, 0.f);
    }
    __syncthreads();
    if (t < 16) {
        float s = bc2[t];
        for (int j = 0; j < 64; j++) s = fmaf(h1[j], Wc2[j * 16 + t], s);
        out[t] = s;
        float u = bu[t];
        for (int c = 0; c < 128; c++) u = fmaf(xf[c], Wu[c * 16 + t], u);
        out[16 + t] = 1.0f / (1.0f + expf(-u));
    }
}

extern "C" void kernel_launch(void* const* d_in, const int* in_sizes, int n_in,
                              void* d_out, int out_size, void* d_ws, size_t ws_size,
                              hipStream_t stream) {
    const float* x    = (const float*)d_in[0];
    const int*   lei  = (const int*)d_in[1];
    const int*   gei  = (const int*)d_in[2];
    const float* W1   = (const float*)d_in[3];
    const float* b1   = (const float*)d_in[4];
    const float* Wg   = (const float*)d_in[5];
    const float* bg   = (const float*)d_in[6];
    const float* Wa   = (const float*)d_in[7];
    const float* atts = (const float*)d_in[8];
    const float* attd = (const float*)d_in[9];
    const float* ba   = (const float*)d_in[10];
    const float* Wp   = (const float*)d_in[11];
    const float* bp   = (const float*)d_in[12];
    const float* Wc1  = (const float*)d_in[13];
    const float* bc1  = (const float*)d_in[14];
    const float* Wc2  = (const float*)d_in[15];
    const float* bc2  = (const float*)d_in[16];
    const float* Wu   = (const float*)d_in[17];
    const float* bu   = (const float*)d_in[18];

    const int* lsrc = lei;
    const int* ldst = lei + EL;
    const int* gsrc = gei;
    const int* gdst = gei + EG;

    uintptr_t base = (uintptr_t)d_ws;
    auto alloc = [&](size_t bytes) { void* p = (void*)base; base += (bytes + 255) & ~(size_t)255; return p; };
    unsigned short* x_loc  = (unsigned short*)alloc((size_t)N_NODES * 128 * 2);
    unsigned char*  xw_g8  = (unsigned char*)alloc((size_t)N_NODES * 128);
    unsigned char*  xw_a8  = (unsigned char*)alloc((size_t)N_NODES * 512);
    unsigned short* xcomb  = (unsigned short*)alloc((size_t)N_NODES * 256 * 2);
    unsigned short* W1t    = (unsigned short*)alloc((size_t)128 * 128 * 2);
    unsigned short* Wgt    = (unsigned short*)alloc((size_t)128 * 128 * 2);
    unsigned short* Wat    = (unsigned short*)alloc((size_t)512 * 128 * 2);
    unsigned short* Wpt    = (unsigned short*)alloc((size_t)128 * 256 * 2);
    float* dinv       = (float*)alloc((size_t)N_NODES * 4);
    float* a_s        = (float*)alloc((size_t)N_NODES * 4 * 4);
    float* a_d        = (float*)alloc((size_t)N_NODES * 4 * 4);
    int*   ghist      = (int*)alloc((size_t)2 * NB * 4);
    int*   bbase      = (int*)alloc((size_t)2 * (NB + 1) * 4);
    int*   gcur       = (int*)alloc((size_t)2 * NB * 4);
    unsigned* ebuf_l  = (unsigned*)alloc((size_t)EL * 4);
    unsigned* ebuf_g  = (unsigned*)alloc((size_t)EG * 4);
    int*   offs_l     = (int*)alloc(((size_t)N_NODES + 1) * 4);
    int*   offs_g     = (int*)alloc(((size_t)N_NODES + 1) * 4);
    unsigned short* csr_l = (unsigned short*)alloc((size_t)EL * 2);
    unsigned short* csr_g = (unsigned short*)alloc((size_t)EG * 2);
    float* sumvec     = (float*)alloc(128 * 4);

    hipMemsetAsync(ghist, 0, (size_t)2 * NB * 4, stream);

    // D1: weights -> bf16^T + bucket histogram
    conv_hist<<<757, 256, 0, stream>>>(W1, W1t, Wg, Wgt, Wa, Wat, Wp, Wpt,
                                       ldst, gdst, ghist);
    // D2: bucket scan (2 blocks, zeroes sumvec) || x_local GEMM (391 blocks)
    scan_gemmx<<<393, 256, 0, stream>>>(ghist, bbase, gcur, sumvec,
                                        x, W1t, b1, x_loc, N_NODES);
    // D3: edge partition (lean)
    bucket_part<<<245, 256, 0, stream>>>(lsrc, ldst, gsrc, gdst, gcur, ebuf_l, ebuf_g);
    // D4: per-bucket CSR + dinv
    bucket_csr<<<392, 256, 0, stream>>>(ebuf_l, ebuf_g, bbase, offs_l, offs_g,
                                        csr_l, csr_g, dinv);
    // D5: Wg + 4 Wa GEMMs, A staged once, xw_g pre-scaled by dinv
    gemm_gw5<<<GB, 256, 0, stream>>>(x_loc, Wgt, Wat, xw_g8, xw_a8, N_NODES,
                                     atts, attd, a_s, a_d, dinv);
    // D6: both gathers
    fused_gather<<<25000, 256, 0, stream>>>(offs_l, csr_l, xw_g8, dinv, bg,
                                            offs_g, csr_g, a_s, a_d, xw_a8, ba, xcomb);
    // D7: pool
    mfma_pool<<<GB, 256, 0, stream>>>(xcomb, Wpt, bp, sumvec, N_NODES);
    // D8: heads
    final_head<<<1, 128, 0, stream>>>(sumvec, Wc1, bc1, Wc2, bc2, Wu, bu,
                                      (float*)d_out);
}